// Round 2
// baseline (1803.461 us; speedup 1.0000x reference)
//
#include <hip/hip_runtime.h>
#include <math.h>

#define BSZ 2
#define SEQ 2048
#define DIM 1024
#define NH 16
#define HDIM 64
#define MR (BSZ*SEQ)   // 4096 rows

typedef __attribute__((ext_vector_type(8))) short bf16x8;
typedef __attribute__((ext_vector_type(4))) float floatx4;

// fp32 -> bf16 round-to-nearest-even (bit pattern in unsigned short)
static __device__ __forceinline__ unsigned short f2bf(float x) {
    unsigned u = __float_as_uint(x);
    u += 0x7fffu + ((u >> 16) & 1u);
    return (unsigned short)(u >> 16);
}
static __device__ __forceinline__ float bf2f(unsigned short h) {
    return __uint_as_float(((unsigned)h) << 16);
}
// truncating fp32 -> bf16 (for V and P where 2^-8 rel error is fine)
static __device__ __forceinline__ unsigned short f2bf_trunc(float x) {
    return (unsigned short)(__float_as_uint(x) >> 16);
}

#define MFMA16(a, b, c) __builtin_amdgcn_mfma_f32_16x16x32_bf16((a), (b), (c), 0, 0, 0)

// ---------------------------------------------------------------------------
// GEMM NT: C[M,N] = A[M,K] * B[N,K]^T   (fp32 vector path — replaced later)
// ---------------------------------------------------------------------------
__global__ __launch_bounds__(256)
void gemm_nt(const float* __restrict__ A, const float* __restrict__ Bw,
             float* __restrict__ C)
{
    const int K = DIM, N = DIM;
    __shared__ float As[16][68];
    __shared__ float Bs[16][68];
    const int tid  = threadIdx.x;
    const int tx   = tid & 15;
    const int ty   = tid >> 4;
    const int lrow = tid >> 2;
    const int lk   = (tid & 3) << 2;
    const int rowBase = blockIdx.y << 6;
    const int colBase = blockIdx.x << 6;
    const float* Ap = A  + (size_t)(rowBase + lrow) * K + lk;
    const float* Bp = Bw + (size_t)(colBase + lrow) * K + lk;
    float acc[4][4] = {};
    for (int k0 = 0; k0 < K; k0 += 16) {
        float4 a4 = *(const float4*)(Ap + k0);
        float4 b4 = *(const float4*)(Bp + k0);
        __syncthreads();
        As[lk+0][lrow]=a4.x; As[lk+1][lrow]=a4.y; As[lk+2][lrow]=a4.z; As[lk+3][lrow]=a4.w;
        Bs[lk+0][lrow]=b4.x; Bs[lk+1][lrow]=b4.y; Bs[lk+2][lrow]=b4.z; Bs[lk+3][lrow]=b4.w;
        __syncthreads();
#pragma unroll
        for (int kk = 0; kk < 16; ++kk) {
            float4 av = *(const float4*)&As[kk][ty<<2];
            float4 bv = *(const float4*)&Bs[kk][tx<<2];
            acc[0][0] += av.x*bv.x; acc[0][1] += av.x*bv.y; acc[0][2] += av.x*bv.z; acc[0][3] += av.x*bv.w;
            acc[1][0] += av.y*bv.x; acc[1][1] += av.y*bv.y; acc[1][2] += av.y*bv.z; acc[1][3] += av.y*bv.w;
            acc[2][0] += av.z*bv.x; acc[2][1] += av.z*bv.y; acc[2][2] += av.z*bv.z; acc[2][3] += av.z*bv.w;
            acc[3][0] += av.w*bv.x; acc[3][1] += av.w*bv.y; acc[3][2] += av.w*bv.z; acc[3][3] += av.w*bv.w;
        }
    }
    float* Cp = C + (size_t)(rowBase + (ty<<2)) * N + colBase + (tx<<2);
#pragma unroll
    for (int i = 0; i < 4; ++i) {
        float4 o4; o4.x=acc[i][0]; o4.y=acc[i][1]; o4.z=acc[i][2]; o4.w=acc[i][3];
        *(float4*)(Cp + (size_t)i * N) = o4;
    }
}

// ---------------------------------------------------------------------------
// Shared MFMA staging pattern:
//   Ks[key 0..63][0..63 = hi(d), 64..127 = lo(d)], row stride 136 shorts
//   (272 B = 16B-aligned; b128 frag reads spread evenly over all 32 banks).
// A-frag (Q/P): lane holds m=lane&15, k=quad*8+j.  B-frag (K/V): n=lane&15,
// k=quad*8+j.  C/D: col=lane&15, row=quad*4+r.
// ---------------------------------------------------------------------------

// def_w[bh, s] = sum_t sigmoid( (q_def[s,:]·k_def[t,:]) / 8 )
// grid (SEQ/64, BSZ*NH), 256 threads (4 waves); wave w owns query rows 16w..+15.
__global__ __launch_bounds__(256, 4)
void defw_mfma(const float* __restrict__ qd, const float* __restrict__ kd,
               float* __restrict__ defw)
{
    __shared__ __align__(16) unsigned short Ks[64][136];
    const int tid = threadIdx.x;
    const int wv = tid >> 6, lane = tid & 63;
    const int c = lane & 15, quad = lane >> 4;
    const int bh = blockIdx.y, b = bh >> 4, h = bh & 15;
    const int qbase = blockIdx.x << 6;
    const int lrow = tid >> 2, lc = (tid & 3) << 4;

    // Q fragments (split hi/lo), held in registers for the whole kernel
    bf16x8 qhi[2], qlo[2];
    {
        const float* qrow = qd + ((size_t)(b*SEQ + qbase + 16*wv + c))*DIM + h*HDIM;
#pragma unroll
        for (int ks = 0; ks < 2; ++ks) {
            float4 f0 = *(const float4*)(qrow + ks*32 + quad*8);
            float4 f1 = *(const float4*)(qrow + ks*32 + quad*8 + 4);
            float xs[8] = {f0.x,f0.y,f0.z,f0.w,f1.x,f1.y,f1.z,f1.w};
#pragma unroll
            for (int j = 0; j < 8; ++j) {
                unsigned short hb = f2bf(xs[j]);
                qhi[ks][j] = (short)hb;
                qlo[ks][j] = (short)f2bf(xs[j] - bf2f(hb));
            }
        }
    }
    float rs[4] = {0.f,0.f,0.f,0.f};
    const float* kbase = kd + ((size_t)(b*SEQ))*DIM + h*HDIM;
    for (int kt = 0; kt < SEQ; kt += 64) {
        __syncthreads();   // previous tile's frag reads done
        {
            const float* kp = kbase + (size_t)(kt + lrow)*DIM + lc;
#pragma unroll
            for (int u = 0; u < 4; ++u) {
                float4 f = *(const float4*)(kp + 4*u);
                ushort4 h4, l4;
                h4.x=f2bf(f.x); l4.x=f2bf(f.x-bf2f(h4.x));
                h4.y=f2bf(f.y); l4.y=f2bf(f.y-bf2f(h4.y));
                h4.z=f2bf(f.z); l4.z=f2bf(f.z-bf2f(h4.z));
                h4.w=f2bf(f.w); l4.w=f2bf(f.w-bf2f(h4.w));
                *(ushort4*)&Ks[lrow][lc + 4*u]      = h4;
                *(ushort4*)&Ks[lrow][64 + lc + 4*u] = l4;
            }
        }
        __syncthreads();   // K tile visible
#pragma unroll
        for (int nk = 0; nk < 4; ++nk) {
            const unsigned short* kr = &Ks[16*nk + c][quad*8];
            bf16x8 bh0 = *(const bf16x8*)(kr);
            bf16x8 bh1 = *(const bf16x8*)(kr + 32);
            bf16x8 bl0 = *(const bf16x8*)(kr + 64);
            bf16x8 bl1 = *(const bf16x8*)(kr + 96);
            floatx4 s = {0.f,0.f,0.f,0.f};
            s = MFMA16(qhi[0], bh0, s);
            s = MFMA16(qhi[1], bh1, s);
            s = MFMA16(qlo[0], bh0, s);
            s = MFMA16(qlo[1], bh1, s);
            s = MFMA16(qhi[0], bl0, s);
            s = MFMA16(qhi[1], bl1, s);
#pragma unroll
            for (int r = 0; r < 4; ++r)
                rs[r] += 1.f / (1.f + __expf(-0.125f * s[r]));
        }
    }
    // reduce over columns (16-lane groups hold cols of rows quad*4+r)
#pragma unroll
    for (int r = 0; r < 4; ++r) {
        float vv = rs[r];
        vv += __shfl_xor(vv, 1, 16);
        vv += __shfl_xor(vv, 2, 16);
        vv += __shfl_xor(vv, 4, 16);
        vv += __shfl_xor(vv, 8, 16);
        rs[r] = vv;
    }
    if (c == 0) {
#pragma unroll
        for (int r = 0; r < 4; ++r)
            defw[(size_t)bh*SEQ + qbase + 16*wv + 4*quad + r] = rs[r];
    }
}

// ---------------------------------------------------------------------------
// Flash attention, MFMA: z[s,t] = (q·k)/8 * defw[t]; softmax_t; O = P·V.
// Split-bf16 QK^T; plain-bf16 PV with V frags loaded directly from global.
// P round-trips through a per-wave LDS slice (no barrier). 2 barriers/tile.
// ---------------------------------------------------------------------------
__global__ __launch_bounds__(256, 3)
void flash_mfma(const float* __restrict__ q, const float* __restrict__ kk,
                const float* __restrict__ v, const float* __restrict__ dwg,
                float* __restrict__ o)
{
    __shared__ __align__(16) unsigned short Ks[64][136];
    __shared__ __align__(16) unsigned short Ps[4][16][72];
    const int tid = threadIdx.x;
    const int wv = tid >> 6, lane = tid & 63;
    const int c = lane & 15, quad = lane >> 4;
    const int bh = blockIdx.y, b = bh >> 4, h = bh & 15;
    const int qbase = blockIdx.x << 6;
    const int lrow = tid >> 2, lc = (tid & 3) << 4;

    bf16x8 qhi[2], qlo[2];
    {
        const float* qrow = q + ((size_t)(b*SEQ + qbase + 16*wv + c))*DIM + h*HDIM;
#pragma unroll
        for (int ks = 0; ks < 2; ++ks) {
            float4 f0 = *(const float4*)(qrow + ks*32 + quad*8);
            float4 f1 = *(const float4*)(qrow + ks*32 + quad*8 + 4);
            float xs[8] = {f0.x,f0.y,f0.z,f0.w,f1.x,f1.y,f1.z,f1.w};
#pragma unroll
            for (int j = 0; j < 8; ++j) {
                unsigned short hb = f2bf(xs[j]);
                qhi[ks][j] = (short)hb;
                qlo[ks][j] = (short)f2bf(xs[j] - bf2f(hb));
            }
        }
    }
    floatx4 Oa[4];
#pragma unroll
    for (int nd = 0; nd < 4; ++nd) Oa[nd] = (floatx4){0.f,0.f,0.f,0.f};
    float mrun[4], lrun[4];
#pragma unroll
    for (int r = 0; r < 4; ++r) { mrun[r] = -3.0e38f; lrun[r] = 0.f; }

    const float* kbase = kk + ((size_t)(b*SEQ))*DIM + h*HDIM;
    const float* vbase = v  + ((size_t)(b*SEQ))*DIM + h*HDIM;

    for (int kt = 0; kt < SEQ; kt += 64) {
        __syncthreads();   // previous tile's Ks frag reads done
        {
            const float* kp = kbase + (size_t)(kt + lrow)*DIM + lc;
#pragma unroll
            for (int u = 0; u < 4; ++u) {
                float4 f = *(const float4*)(kp + 4*u);
                ushort4 h4, l4;
                h4.x=f2bf(f.x); l4.x=f2bf(f.x-bf2f(h4.x));
                h4.y=f2bf(f.y); l4.y=f2bf(f.y-bf2f(h4.y));
                h4.z=f2bf(f.z); l4.z=f2bf(f.z-bf2f(h4.z));
                h4.w=f2bf(f.w); l4.w=f2bf(f.w-bf2f(h4.w));
                *(ushort4*)&Ks[lrow][lc + 4*u]      = h4;
                *(ushort4*)&Ks[lrow][64 + lc + 4*u] = l4;
            }
        }
        // per-key defeasible weights for this tile (L2-hot scalar loads)
        float dwv[4];
#pragma unroll
        for (int n = 0; n < 4; ++n)
            dwv[n] = dwg[(size_t)bh*SEQ + kt + 16*n + c];
        __syncthreads();   // K tile visible

        // QK^T (split bf16, 3-term)
        floatx4 z[4];
#pragma unroll
        for (int nk = 0; nk < 4; ++nk) {
            const unsigned short* kr = &Ks[16*nk + c][quad*8];
            bf16x8 bh0 = *(const bf16x8*)(kr);
            bf16x8 bh1 = *(const bf16x8*)(kr + 32);
            bf16x8 bl0 = *(const bf16x8*)(kr + 64);
            bf16x8 bl1 = *(const bf16x8*)(kr + 96);
            floatx4 s = {0.f,0.f,0.f,0.f};
            s = MFMA16(qhi[0], bh0, s);
            s = MFMA16(qhi[1], bh1, s);
            s = MFMA16(qlo[0], bh0, s);
            s = MFMA16(qlo[1], bh1, s);
            s = MFMA16(qhi[0], bl0, s);
            s = MFMA16(qhi[1], bl1, s);
            float w = 0.125f * dwv[nk];
#pragma unroll
            for (int r = 0; r < 4; ++r) z[nk][r] = s[r] * w;
        }

        // V fragments straight from global fp32 (converted below)
        float vsf[8][8];
#pragma unroll
        for (int nd = 0; nd < 4; ++nd)
#pragma unroll
            for (int ks = 0; ks < 2; ++ks)
#pragma unroll
                for (int j = 0; j < 8; ++j)
                    vsf[nd*2+ks][j] =
                        vbase[(size_t)(kt + ks*32 + quad*8 + j)*DIM + 16*nd + c];

        // online softmax, fully in registers (width-16 butterflies)
        float alpha[4];
#pragma unroll
        for (int r = 0; r < 4; ++r) {
            float tm = fmaxf(fmaxf(z[0][r], z[1][r]), fmaxf(z[2][r], z[3][r]));
            tm = fmaxf(tm, __shfl_xor(tm, 1, 16));
            tm = fmaxf(tm, __shfl_xor(tm, 2, 16));
            tm = fmaxf(tm, __shfl_xor(tm, 4, 16));
            tm = fmaxf(tm, __shfl_xor(tm, 8, 16));
            float mn = fmaxf(mrun[r], tm);
            alpha[r] = __expf(mrun[r] - mn);
            mrun[r] = mn;
        }
#pragma unroll
        for (int r = 0; r < 4; ++r) {
            float rsum = 0.f;
#pragma unroll
            for (int n = 0; n < 4; ++n) {
                z[n][r] = __expf(z[n][r] - mrun[r]);
                rsum += z[n][r];
            }
            rsum += __shfl_xor(rsum, 1, 16);
            rsum += __shfl_xor(rsum, 2, 16);
            rsum += __shfl_xor(rsum, 4, 16);
            rsum += __shfl_xor(rsum, 8, 16);
            lrun[r] = lrun[r] * alpha[r] + rsum;
        }
        // P -> per-wave LDS slice (bf16 trunc), C-layout -> A-layout
#pragma unroll
        for (int n = 0; n < 4; ++n)
#pragma unroll
            for (int r = 0; r < 4; ++r)
                Ps[wv][4*quad + r][16*n + c] = f2bf_trunc(z[n][r]);
        // rescale O
#pragma unroll
        for (int nd = 0; nd < 4; ++nd)
#pragma unroll
            for (int r = 0; r < 4; ++r)
                Oa[nd][r] *= alpha[r];
        // convert V frags (trunc bf16)
        bf16x8 vfr[8];
#pragma unroll
        for (int f = 0; f < 8; ++f)
#pragma unroll
            for (int j = 0; j < 8; ++j)
                vfr[f][j] = (short)f2bf_trunc(vsf[f][j]);
        // P A-frags (same wave wrote all 16 rows; lgkmcnt ordering suffices)
        bf16x8 pa0 = *(const bf16x8*)&Ps[wv][c][quad*8];
        bf16x8 pa1 = *(const bf16x8*)&Ps[wv][c][32 + quad*8];
        // PV
#pragma unroll
        for (int nd = 0; nd < 4; ++nd) {
            Oa[nd] = MFMA16(pa0, vfr[nd*2+0], Oa[nd]);
            Oa[nd] = MFMA16(pa1, vfr[nd*2+1], Oa[nd]);
        }
    }
    float invl[4];
#pragma unroll
    for (int r = 0; r < 4; ++r) invl[r] = 1.f / lrun[r];
    float* orow = o + ((size_t)(b*SEQ + qbase + 16*wv + 4*quad))*DIM + h*HDIM;
#pragma unroll
    for (int nd = 0; nd < 4; ++nd)
#pragma unroll
        for (int r = 0; r < 4; ++r)
            orow[(size_t)r*DIM + 16*nd + c] = Oa[nd][r] * invl[r];
}

// ---------------------------------------------------------------------------
extern "C" void kernel_launch(void* const* d_in, const int* in_sizes, int n_in,
                              void* d_out, int out_size, void* d_ws, size_t ws_size,
                              hipStream_t stream)
{
    (void)in_sizes; (void)n_in; (void)out_size; (void)ws_size;
    const float* qi     = (const float*)d_in[0];
    const float* ki     = (const float*)d_in[1];
    const float* vi     = (const float*)d_in[2];
    const float* Wq     = (const float*)d_in[3];
    const float* Wq_def = (const float*)d_in[4];
    const float* Wk     = (const float*)d_in[5];
    const float* Wk_def = (const float*)d_in[6];
    const float* Wv     = (const float*)d_in[7];
    const float* Wo     = (const float*)d_in[8];
    float* out = (float*)d_out;

    const size_t NB = (size_t)MR * DIM;   // 16 MiB each
    float* bufA = (float*)d_ws;           // q
    float* bufB = bufA + NB;              // k
    float* bufC = bufB + NB;              // q_def, later v
    float* bufD = bufC + NB;              // k_def, later attended
    float* dw   = bufD + NB;              // def_w [BSZ*NH*SEQ]

    dim3 gGemm(DIM/64, MR/64);            // (16, 64)
    dim3 gAttn(SEQ/64, BSZ*NH);           // (32, 32)

    gemm_nt<<<gGemm, 256, 0, stream>>>(qi, Wq_def, bufC);
    gemm_nt<<<gGemm, 256, 0, stream>>>(ki, Wk_def, bufD);
    defw_mfma<<<gAttn, 256, 0, stream>>>(bufC, bufD, dw);
    gemm_nt<<<gGemm, 256, 0, stream>>>(qi, Wq, bufA);
    gemm_nt<<<gGemm, 256, 0, stream>>>(ki, Wk, bufB);
    gemm_nt<<<gGemm, 256, 0, stream>>>(vi, Wv, bufC);
    flash_mfma<<<gAttn, 256, 0, stream>>>(bufA, bufB, bufC, dw, bufD);
    gemm_nt<<<gGemm, 256, 0, stream>>>(bufD, Wo, out);
}

// Round 3
// 583.086 us; speedup vs baseline: 3.0930x; 3.0930x over previous
//
#include <hip/hip_runtime.h>
#include <math.h>

#define BSZ 2
#define SEQ 2048
#define DIM 1024
#define NH 16
#define HDIM 64
#define MR (BSZ*SEQ)   // 4096 rows

typedef __attribute__((ext_vector_type(8))) short bf16x8;
typedef __attribute__((ext_vector_type(4))) float floatx4;

static __device__ __forceinline__ unsigned short f2bf(float x) {
    unsigned u = __float_as_uint(x);
    u += 0x7fffu + ((u >> 16) & 1u);
    return (unsigned short)(u >> 16);
}
static __device__ __forceinline__ float bf2f(unsigned short h) {
    return __uint_as_float(((unsigned)h) << 16);
}
#define MFMA16(a,b,c) __builtin_amdgcn_mfma_f32_16x16x32_bf16((a),(b),(c),0,0,0)

// ---------------------------------------------------------------------------
// conv_split: fp32 [rows][1024] -> bf16 [rows][2048] as [hi | lo]
// blockIdx.y selects one of 6 matrices.
// ---------------------------------------------------------------------------
__global__ __launch_bounds__(256)
void conv_split(const float* p0, const float* p1, const float* p2,
                const float* p3, const float* p4, const float* p5,
                unsigned short* o0, unsigned short* o1, unsigned short* o2,
                unsigned short* o3, unsigned short* o4, unsigned short* o5,
                int r0, int r1, int r2, int r3, int r4, int r5)
{
    const float* pin; unsigned short* pout; int rows;
    switch (blockIdx.y) {
        case 0: pin=p0; pout=o0; rows=r0; break;
        case 1: pin=p1; pout=o1; rows=r1; break;
        case 2: pin=p2; pout=o2; rows=r2; break;
        case 3: pin=p3; pout=o3; rows=r3; break;
        case 4: pin=p4; pout=o4; rows=r4; break;
        default: pin=p5; pout=o5; rows=r5; break;
    }
    size_t idx = (size_t)blockIdx.x * 256 + threadIdx.x;   // group of 4 floats
    if (idx * 4 >= (size_t)rows * DIM) return;
    size_t row = (idx * 4) >> 10;
    int col = (int)((idx * 4) & 1023);
    float4 f = *(const float4*)(pin + idx * 4);
    ushort4 h, l;
    h.x = f2bf(f.x); l.x = f2bf(f.x - bf2f(h.x));
    h.y = f2bf(f.y); l.y = f2bf(f.y - bf2f(h.y));
    h.z = f2bf(f.z); l.z = f2bf(f.z - bf2f(h.z));
    h.w = f2bf(f.w); l.w = f2bf(f.w - bf2f(h.w));
    *(ushort4*)(pout + row * 2048 + col)        = h;
    *(ushort4*)(pout + row * 2048 + 1024 + col) = l;
}

// conv_hi: fp32 flat -> bf16 flat (hi only), 3 matrices via blockIdx.y
__global__ __launch_bounds__(256)
void conv_hi(const float* p0, const float* p1, const float* p2,
             unsigned short* o0, unsigned short* o1, unsigned short* o2,
             int n0, int n1, int n2)
{
    const float* pin; unsigned short* pout; int n;
    switch (blockIdx.y) {
        case 0: pin=p0; pout=o0; n=n0; break;
        case 1: pin=p1; pout=o1; n=n1; break;
        default: pin=p2; pout=o2; n=n2; break;
    }
    size_t idx = (size_t)blockIdx.x * 256 + threadIdx.x;
    if (idx * 4 >= (size_t)n) return;
    float4 f = *(const float4*)(pin + idx * 4);
    ushort4 h;
    h.x = f2bf(f.x); h.y = f2bf(f.y); h.z = f2bf(f.z); h.w = f2bf(f.w);
    *(ushort4*)(pout + idx * 4) = h;
}

// ---------------------------------------------------------------------------
// bf16 MFMA GEMM: C[M=4096 x 1024] = A[.][K] * B[1024][K]^T  (both row-major,
// A' = [Ah|Al], B' = [Bh|Bl] when SPLIT3: 48 k-blocks give hh + lh + hl).
// 128x128 tile, 256 thr (4 waves as 2x2 of 64x64), BK=64, reg-prefetch.
// blockIdx.z selects one of two (A,B,C) problem instances.
// ---------------------------------------------------------------------------
template<bool OUT_BF16, bool SPLIT3>
__global__ __launch_bounds__(256)
void gemm_mfma(const unsigned short* __restrict__ A0, const unsigned short* __restrict__ A1,
               const unsigned short* __restrict__ B0, const unsigned short* __restrict__ B1,
               void* C0v, void* C1v, int lda, int ldb, int nkb)
{
    const unsigned short* A = blockIdx.z ? A1 : A0;
    const unsigned short* B = blockIdx.z ? B1 : B0;
    float* Cf = (float*)(blockIdx.z ? C1v : C0v);
    unsigned short* Cb = (unsigned short*)(blockIdx.z ? C1v : C0v);

    __shared__ __align__(16) unsigned short As[128][72];
    __shared__ __align__(16) unsigned short Bs[128][72];

    const int tid = threadIdx.x;
    const int lane = tid & 63, wv = tid >> 6;
    const int c = lane & 15, quad = lane >> 4;
    const int wm = wv >> 1, wn = wv & 1;
    const int rowBase = blockIdx.y << 7;
    const int colBase = blockIdx.x << 7;

    floatx4 acc[4][4];
#pragma unroll
    for (int i = 0; i < 4; ++i)
#pragma unroll
        for (int j = 0; j < 4; ++j) acc[i][j] = (floatx4){0.f,0.f,0.f,0.f};

    bf16x8 ar[4], br[4];
    // prefetch k-block 0
    {
        int aoff = 0, boff = 0;
#pragma unroll
        for (int i = 0; i < 4; ++i) {
            int f = tid + (i << 8);
            int r = f >> 3, kbk = (f & 7) << 3;
            ar[i] = *(const bf16x8*)(A + (size_t)(rowBase + r) * lda + aoff + kbk);
            br[i] = *(const bf16x8*)(B + (size_t)(colBase + r) * ldb + boff + kbk);
        }
    }
    for (int kb = 0; kb < nkb; ++kb) {
        __syncthreads();
#pragma unroll
        for (int i = 0; i < 4; ++i) {
            int f = tid + (i << 8);
            int r = f >> 3, kbk = (f & 7) << 3;
            *(bf16x8*)&As[r][kbk] = ar[i];
            *(bf16x8*)&Bs[r][kbk] = br[i];
        }
        __syncthreads();
        if (kb + 1 < nkb) {
            int kn = kb + 1, aoff, boff;
            if (SPLIT3) {
                int t = kn >> 4, kk = (kn & 15) << 6;
                aoff = ((t == 1) ? 1024 : 0) + kk;
                boff = ((t == 2) ? 1024 : 0) + kk;
            } else { aoff = boff = kn << 6; }
#pragma unroll
            for (int i = 0; i < 4; ++i) {
                int f = tid + (i << 8);
                int r = f >> 3, kbk = (f & 7) << 3;
                ar[i] = *(const bf16x8*)(A + (size_t)(rowBase + r) * lda + aoff + kbk);
                br[i] = *(const bf16x8*)(B + (size_t)(colBase + r) * ldb + boff + kbk);
            }
        }
#pragma unroll
        for (int ks = 0; ks < 2; ++ks) {
            bf16x8 af[4], bfr[4];
#pragma unroll
            for (int i = 0; i < 4; ++i) {
                af[i]  = *(const bf16x8*)&As[wm*64 + i*16 + c][ks*32 + quad*8];
                bfr[i] = *(const bf16x8*)&Bs[wn*64 + i*16 + c][ks*32 + quad*8];
            }
#pragma unroll
            for (int mi = 0; mi < 4; ++mi)
#pragma unroll
                for (int ni = 0; ni < 4; ++ni)
                    acc[mi][ni] = MFMA16(af[mi], bfr[ni], acc[mi][ni]);
        }
    }
    const int row0 = rowBase + wm*64 + quad*4;
    const int col0 = colBase + wn*64 + c;
#pragma unroll
    for (int mi = 0; mi < 4; ++mi)
#pragma unroll
        for (int r = 0; r < 4; ++r) {
            size_t ro = (size_t)(row0 + mi*16 + r) * 1024 + col0;
#pragma unroll
            for (int ni = 0; ni < 4; ++ni) {
                if (OUT_BF16) Cb[ro + ni*16] = f2bf(acc[mi][ni][r]);
                else          Cf[ro + ni*16] = acc[mi][ni][r];
            }
        }
}

// ---------------------------------------------------------------------------
// def_w (unchanged from round 2 — verified)
// ---------------------------------------------------------------------------
__global__ __launch_bounds__(256)
void defw_mfma(const float* __restrict__ qd, const float* __restrict__ kd,
               float* __restrict__ defw)
{
    __shared__ __align__(16) unsigned short Ks[64][136];
    const int tid = threadIdx.x;
    const int wv = tid >> 6, lane = tid & 63;
    const int c = lane & 15, quad = lane >> 4;
    const int bh = blockIdx.y, b = bh >> 4, h = bh & 15;
    const int qbase = blockIdx.x << 6;
    const int lrow = tid >> 2, lc = (tid & 3) << 4;

    bf16x8 qhi[2], qlo[2];
    {
        const float* qrow = qd + ((size_t)(b*SEQ + qbase + 16*wv + c))*DIM + h*HDIM;
#pragma unroll
        for (int ks = 0; ks < 2; ++ks) {
            float4 f0 = *(const float4*)(qrow + ks*32 + quad*8);
            float4 f1 = *(const float4*)(qrow + ks*32 + quad*8 + 4);
            float xs[8] = {f0.x,f0.y,f0.z,f0.w,f1.x,f1.y,f1.z,f1.w};
#pragma unroll
            for (int j = 0; j < 8; ++j) {
                unsigned short hb = f2bf(xs[j]);
                qhi[ks][j] = (short)hb;
                qlo[ks][j] = (short)f2bf(xs[j] - bf2f(hb));
            }
        }
    }
    float rs[4] = {0.f,0.f,0.f,0.f};
    const float* kbase = kd + ((size_t)(b*SEQ))*DIM + h*HDIM;
    for (int kt = 0; kt < SEQ; kt += 64) {
        __syncthreads();
        {
            const float* kp = kbase + (size_t)(kt + lrow)*DIM + lc;
#pragma unroll
            for (int u = 0; u < 4; ++u) {
                float4 f = *(const float4*)(kp + 4*u);
                ushort4 h4, l4;
                h4.x=f2bf(f.x); l4.x=f2bf(f.x-bf2f(h4.x));
                h4.y=f2bf(f.y); l4.y=f2bf(f.y-bf2f(h4.y));
                h4.z=f2bf(f.z); l4.z=f2bf(f.z-bf2f(h4.z));
                h4.w=f2bf(f.w); l4.w=f2bf(f.w-bf2f(h4.w));
                *(ushort4*)&Ks[lrow][lc + 4*u]      = h4;
                *(ushort4*)&Ks[lrow][64 + lc + 4*u] = l4;
            }
        }
        __syncthreads();
#pragma unroll
        for (int nk = 0; nk < 4; ++nk) {
            const unsigned short* kr = &Ks[16*nk + c][quad*8];
            bf16x8 bh0 = *(const bf16x8*)(kr);
            bf16x8 bh1 = *(const bf16x8*)(kr + 32);
            bf16x8 bl0 = *(const bf16x8*)(kr + 64);
            bf16x8 bl1 = *(const bf16x8*)(kr + 96);
            floatx4 s = {0.f,0.f,0.f,0.f};
            s = MFMA16(qhi[0], bh0, s);
            s = MFMA16(qhi[1], bh1, s);
            s = MFMA16(qlo[0], bh0, s);
            s = MFMA16(qlo[1], bh1, s);
            s = MFMA16(qhi[0], bl0, s);
            s = MFMA16(qhi[1], bl1, s);
#pragma unroll
            for (int r = 0; r < 4; ++r)
                rs[r] += 1.f / (1.f + __expf(-0.125f * s[r]));
        }
    }
#pragma unroll
    for (int r = 0; r < 4; ++r) {
        float vv = rs[r];
        vv += __shfl_xor(vv, 1, 16);
        vv += __shfl_xor(vv, 2, 16);
        vv += __shfl_xor(vv, 4, 16);
        vv += __shfl_xor(vv, 8, 16);
        rs[r] = vv;
    }
    if (c == 0) {
#pragma unroll
        for (int r = 0; r < 4; ++r)
            defw[(size_t)bh*SEQ + qbase + 16*wv + 4*quad + r] = rs[r];
    }
}

// ---------------------------------------------------------------------------
// Flash attention: q,k fp32 (split on load), v bf16, out bf16.
// V staged to LDS transposed with XOR swizzle (conflict-free), no big arrays.
// ---------------------------------------------------------------------------
__global__ __launch_bounds__(256)
void flash_mfma(const float* __restrict__ q, const float* __restrict__ kk,
                const unsigned short* __restrict__ v, const float* __restrict__ dwg,
                unsigned short* __restrict__ o)
{
    __shared__ __align__(16) unsigned short Ks[64][136];
    __shared__ __align__(16) unsigned short Vs[64][72];
    __shared__ __align__(16) unsigned short Ps[4][16][72];
    const int tid = threadIdx.x;
    const int wv = tid >> 6, lane = tid & 63;
    const int c = lane & 15, quad = lane >> 4;
    const int bh = blockIdx.y, b = bh >> 4, h = bh & 15;
    const int qbase = blockIdx.x << 6;
    const int lrow = tid >> 2, lc = (tid & 3) << 4;

    bf16x8 qhi[2], qlo[2];
    {
        const float* qrow = q + ((size_t)(b*SEQ + qbase + 16*wv + c))*DIM + h*HDIM;
#pragma unroll
        for (int ks = 0; ks < 2; ++ks) {
            float4 f0 = *(const float4*)(qrow + ks*32 + quad*8);
            float4 f1 = *(const float4*)(qrow + ks*32 + quad*8 + 4);
            float xs[8] = {f0.x,f0.y,f0.z,f0.w,f1.x,f1.y,f1.z,f1.w};
#pragma unroll
            for (int j = 0; j < 8; ++j) {
                unsigned short hb = f2bf(xs[j]);
                qhi[ks][j] = (short)hb;
                qlo[ks][j] = (short)f2bf(xs[j] - bf2f(hb));
            }
        }
    }
    floatx4 Oa[4];
#pragma unroll
    for (int nd = 0; nd < 4; ++nd) Oa[nd] = (floatx4){0.f,0.f,0.f,0.f};
    float mrun[4], lrun[4];
#pragma unroll
    for (int r = 0; r < 4; ++r) { mrun[r] = -3.0e38f; lrun[r] = 0.f; }

    const float* kbase = kk + ((size_t)(b*SEQ))*DIM + h*HDIM;
    const unsigned short* vbase = v + ((size_t)(b*SEQ))*DIM + h*HDIM;

    for (int kt = 0; kt < SEQ; kt += 64) {
        __syncthreads();   // prev tile frag reads done
        {   // K staging: hi|lo split
            const float* kp = kbase + (size_t)(kt + lrow)*DIM + lc;
#pragma unroll
            for (int u = 0; u < 4; ++u) {
                float4 f = *(const float4*)(kp + 4*u);
                ushort4 h4, l4;
                h4.x=f2bf(f.x); l4.x=f2bf(f.x-bf2f(h4.x));
                h4.y=f2bf(f.y); l4.y=f2bf(f.y-bf2f(h4.y));
                h4.z=f2bf(f.z); l4.z=f2bf(f.z-bf2f(h4.z));
                h4.w=f2bf(f.w); l4.w=f2bf(f.w-bf2f(h4.w));
                *(ushort4*)&Ks[lrow][lc + 4*u]      = h4;
                *(ushort4*)&Ks[lrow][64 + lc + 4*u] = l4;
            }
        }
        {   // V staging: transpose into Vs[d][t ^ ((d>>3 & 7)<<3)]
#pragma unroll
            for (int i = 0; i < 2; ++i) {
                int f = tid + (i << 8);
                int trow = f >> 3, chunk = f & 7;
                bf16x8 vv = *(const bf16x8*)(vbase + (size_t)(kt + trow)*DIM + chunk*8);
                int tsw = trow ^ (chunk << 3);
#pragma unroll
                for (int j = 0; j < 8; ++j)
                    Vs[chunk*8 + j][tsw] = (unsigned short)vv[j];
            }
        }
        float dwv[4];
#pragma unroll
        for (int n = 0; n < 4; ++n)
            dwv[n] = dwg[(size_t)bh*SEQ + kt + 16*n + c];
        __syncthreads();   // K,V tiles visible

        floatx4 z[4];
#pragma unroll
        for (int nk = 0; nk < 4; ++nk) {
            const unsigned short* kr = &Ks[16*nk + c][quad*8];
            bf16x8 bh0 = *(const bf16x8*)(kr);
            bf16x8 bh1 = *(const bf16x8*)(kr + 32);
            bf16x8 bl0 = *(const bf16x8*)(kr + 64);
            bf16x8 bl1 = *(const bf16x8*)(kr + 96);
            floatx4 s = {0.f,0.f,0.f,0.f};
            s = MFMA16(qhi[0], bh0, s);
            s = MFMA16(qhi[1], bh1, s);
            s = MFMA16(qlo[0], bh0, s);
            s = MFMA16(qlo[1], bh1, s);
            s = MFMA16(qhi[0], bl0, s);
            s = MFMA16(qhi[1], bl1, s);
            float w = 0.125f * dwv[nk];
#pragma unroll
            for (int r = 0; r < 4; ++r) z[nk][r] = s[r] * w;
        }
        // online softmax in registers
        float alpha[4];
#pragma unroll
        for (int r = 0; r < 4; ++r) {
            float tm = fmaxf(fmaxf(z[0][r], z[1][r]), fmaxf(z[2][r], z[3][r]));
            tm = fmaxf(tm, __shfl_xor(tm, 1, 16));
            tm = fmaxf(tm, __shfl_xor(tm, 2, 16));
            tm = fmaxf(tm, __shfl_xor(tm, 4, 16));
            tm = fmaxf(tm, __shfl_xor(tm, 8, 16));
            float mn = fmaxf(mrun[r], tm);
            alpha[r] = __expf(mrun[r] - mn);
            mrun[r] = mn;
        }
#pragma unroll
        for (int r = 0; r < 4; ++r) {
            float rsum = 0.f;
#pragma unroll
            for (int n = 0; n < 4; ++n) {
                z[n][r] = __expf(z[n][r] - mrun[r]);
                rsum += z[n][r];
            }
            rsum += __shfl_xor(rsum, 1, 16);
            rsum += __shfl_xor(rsum, 2, 16);
            rsum += __shfl_xor(rsum, 4, 16);
            rsum += __shfl_xor(rsum, 8, 16);
            lrun[r] = lrun[r] * alpha[r] + rsum;
        }
        // P -> per-wave LDS slice (C-layout -> A-layout), no barrier needed
#pragma unroll
        for (int n = 0; n < 4; ++n)
#pragma unroll
            for (int r = 0; r < 4; ++r)
                Ps[wv][4*quad + r][16*n + c] = f2bf(z[n][r]);
#pragma unroll
        for (int nd = 0; nd < 4; ++nd)
#pragma unroll
            for (int r = 0; r < 4; ++r)
                Oa[nd][r] *= alpha[r];
        bf16x8 pa0 = *(const bf16x8*)&Ps[wv][c][quad*8];
        bf16x8 pa1 = *(const bf16x8*)&Ps[wv][c][32 + quad*8];
#pragma unroll
        for (int nd = 0; nd < 4; ++nd) {
            int zsw = ((2*nd + (c >> 3)) & 7) << 3;
            const int d = 16*nd + c;
            bf16x8 v0 = *(const bf16x8*)&Vs[d][(quad*8) ^ zsw];
            bf16x8 v1 = *(const bf16x8*)&Vs[d][(32 + quad*8) ^ zsw];
            Oa[nd] = MFMA16(pa0, v0, Oa[nd]);
            Oa[nd] = MFMA16(pa1, v1, Oa[nd]);
        }
    }
    float invl[4];
#pragma unroll
    for (int r = 0; r < 4; ++r) invl[r] = 1.f / lrun[r];
    unsigned short* orow = o + ((size_t)(b*SEQ + qbase + 16*wv + 4*quad))*DIM + h*HDIM;
#pragma unroll
    for (int nd = 0; nd < 4; ++nd)
#pragma unroll
        for (int r = 0; r < 4; ++r)
            orow[(size_t)r*DIM + 16*nd + c] = f2bf(Oa[nd][r] * invl[r]);
}

// ---------------------------------------------------------------------------
extern "C" void kernel_launch(void* const* d_in, const int* in_sizes, int n_in,
                              void* d_out, int out_size, void* d_ws, size_t ws_size,
                              hipStream_t stream)
{
    (void)in_sizes; (void)n_in; (void)out_size; (void)ws_size;
    const float* qi     = (const float*)d_in[0];
    const float* ki     = (const float*)d_in[1];
    const float* vi     = (const float*)d_in[2];
    const float* Wq     = (const float*)d_in[3];
    const float* Wq_def = (const float*)d_in[4];
    const float* Wk     = (const float*)d_in[5];
    const float* Wk_def = (const float*)d_in[6];
    const float* Wv     = (const float*)d_in[7];
    const float* Wo     = (const float*)d_in[8];
    float* out = (float*)d_out;

    char* ws = (char*)d_ws;
    const size_t MB = 1024 * 1024;
    unsigned short* Aq  = (unsigned short*)(ws +  0*MB);  // [4096][2048] hi|lo, 16 MB
    unsigned short* Ak  = (unsigned short*)(ws + 16*MB);  // 16 MB
    unsigned short* Bqd = (unsigned short*)(ws + 32*MB);  // [1024][2048], 4 MB
    unsigned short* Bkd = (unsigned short*)(ws + 36*MB);
    unsigned short* Bq  = (unsigned short*)(ws + 40*MB);
    unsigned short* Bk  = (unsigned short*)(ws + 44*MB);
    float*          qd  = (float*)(ws + 48*MB);           // 16 MB, later q
    float*          kd  = (float*)(ws + 64*MB);           // 16 MB, later k
    float*          dw  = (float*)(ws + 80*MB);           // 256 KB
    // overlays (after producers of the region are dead):
    unsigned short* Av  = (unsigned short*)(ws + 32*MB);  // 8 MB  (over Bqd/Bkd)
    unsigned short* Bv  = (unsigned short*)(ws + 40*MB);  // 2 MB  (over Bq)
    unsigned short* Bo  = (unsigned short*)(ws + 42*MB);  // 2 MB
    unsigned short* vbf = (unsigned short*)(ws +  0*MB);  // 8 MB  (over Aq)
    unsigned short* att = (unsigned short*)(ws +  8*MB);  // 8 MB

    dim3 cb(256);
    dim3 gP(DIM/128, MR/128, 2);   // (8, 32, 2)
    dim3 gS(DIM/128, MR/128, 1);   // (8, 32, 1)
    dim3 gA(SEQ/64, BSZ*NH);       // (32, 32)

    // 1. split-convert qi, ki and the 4 precision-critical weights
    conv_split<<<dim3(4096, 6), cb, 0, stream>>>(
        qi, ki, Wq, Wq_def, Wk, Wk_def,
        Aq, Ak, Bq, Bqd, Bk, Bkd,
        MR, MR, DIM, DIM, DIM, DIM);
    // 2. q_def, k_def  (split-bf16 3-term GEMM)
    gemm_mfma<false, true><<<gP, cb, 0, stream>>>(Aq, Ak, Bqd, Bkd, qd, kd, 2048, 2048, 48);
    // 3. defeasible weights
    defw_mfma<<<gA, cb, 0, stream>>>(qd, kd, dw);
    // 4. q, k (overwrite qd, kd)
    gemm_mfma<false, true><<<gP, cb, 0, stream>>>(Aq, Ak, Bq, Bk, qd, kd, 2048, 2048, 48);
    // 5. hi-only converts for v path (B' region now dead)
    conv_hi<<<dim3(4096, 3), cb, 0, stream>>>(vi, Wv, Wo, Av, Bv, Bo,
                                              MR*DIM, DIM*DIM, DIM*DIM);
    // 6. v projection -> bf16 (Aq region dead)
    gemm_mfma<true, false><<<gS, cb, 0, stream>>>(Av, Av, Bv, Bv, vbf, vbf, 1024, 1024, 16);
    // 7. attention
    flash_mfma<<<gA, cb, 0, stream>>>(qd, kd, vbf, dw, att);
    // 8. output projection
    gemm_mfma<false, false><<<gS, cb, 0, stream>>>(att, att, Bo, Bo, out, out, 1024, 1024, 16);
}

// Round 4
// 533.160 us; speedup vs baseline: 3.3826x; 1.0936x over previous
//
#include <hip/hip_runtime.h>
#include <math.h>

#define BSZ 2
#define SEQ 2048
#define DIM 1024
#define NH 16
#define HDIM 64
#define MR (BSZ*SEQ)   // 4096 rows

typedef __attribute__((ext_vector_type(8))) short bf16x8;
typedef __attribute__((ext_vector_type(4))) float floatx4;

static __device__ __forceinline__ unsigned short f2bf(float x) {
    unsigned u = __float_as_uint(x);
    u += 0x7fffu + ((u >> 16) & 1u);
    return (unsigned short)(u >> 16);
}
static __device__ __forceinline__ float bf2f(unsigned short h) {
    return __uint_as_float(((unsigned)h) << 16);
}
#define MFMA16(a,b,c) __builtin_amdgcn_mfma_f32_16x16x32_bf16((a),(b),(c),0,0,0)

// ---------------------------------------------------------------------------
// conv_split: fp32 [rows][1024] -> bf16 [rows][2048] as [hi | lo]
// gridDim.y slots select matrices (unused slots: rows=0).
// ---------------------------------------------------------------------------
__global__ __launch_bounds__(256)
void conv_split(const float* p0, const float* p1, const float* p2,
                const float* p3,
                unsigned short* o0, unsigned short* o1, unsigned short* o2,
                unsigned short* o3,
                int r0, int r1, int r2, int r3)
{
    const float* pin; unsigned short* pout; int rows;
    switch (blockIdx.y) {
        case 0: pin=p0; pout=o0; rows=r0; break;
        case 1: pin=p1; pout=o1; rows=r1; break;
        case 2: pin=p2; pout=o2; rows=r2; break;
        default: pin=p3; pout=o3; rows=r3; break;
    }
    size_t idx = (size_t)blockIdx.x * 256 + threadIdx.x;   // group of 4 floats
    if (idx * 4 >= (size_t)rows * DIM) return;
    size_t row = (idx * 4) >> 10;
    int col = (int)((idx * 4) & 1023);
    float4 f = *(const float4*)(pin + idx * 4);
    ushort4 h, l;
    h.x = f2bf(f.x); l.x = f2bf(f.x - bf2f(h.x));
    h.y = f2bf(f.y); l.y = f2bf(f.y - bf2f(h.y));
    h.z = f2bf(f.z); l.z = f2bf(f.z - bf2f(h.z));
    h.w = f2bf(f.w); l.w = f2bf(f.w - bf2f(h.w));
    *(ushort4*)(pout + row * 2048 + col)        = h;
    *(ushort4*)(pout + row * 2048 + 1024 + col) = l;
}

// conv_hi: fp32 flat -> bf16 flat (hi only), 3 matrices via blockIdx.y
__global__ __launch_bounds__(256)
void conv_hi(const float* p0, const float* p1, const float* p2,
             unsigned short* o0, unsigned short* o1, unsigned short* o2,
             int n0, int n1, int n2)
{
    const float* pin; unsigned short* pout; int n;
    switch (blockIdx.y) {
        case 0: pin=p0; pout=o0; n=n0; break;
        case 1: pin=p1; pout=o1; n=n1; break;
        default: pin=p2; pout=o2; n=n2; break;
    }
    size_t idx = (size_t)blockIdx.x * 256 + threadIdx.x;
    if (idx * 4 >= (size_t)n) return;
    float4 f = *(const float4*)(pin + idx * 4);
    ushort4 h;
    h.x = f2bf(f.x); h.y = f2bf(f.y); h.z = f2bf(f.z); h.w = f2bf(f.w);
    *(ushort4*)(pout + idx * 4) = h;
}

// ---------------------------------------------------------------------------
// bf16 MFMA GEMM: C[M x 1024] = A[.][K] * B[1024][K]^T, 128x128 tile, BK=64.
// SPLIT3: A'=[Ah|Al], B'=[Bh|Bl], 48 k-blocks -> hh + lh + hl.
// EPI: 0 = fp32 row-major [.][1024]
//      1 = split-bf16 per-(b,h): out[bh][s][0..63 hi | 64..127 lo]
//      2 = V^T per-(b,h):        out[bh][d][s]   (bf16)
// ---------------------------------------------------------------------------
template<int EPI, bool SPLIT3>
__global__ __launch_bounds__(256)
void gemm_mfma(const unsigned short* __restrict__ A0, const unsigned short* __restrict__ A1,
               const unsigned short* __restrict__ B0, const unsigned short* __restrict__ B1,
               void* C0v, void* C1v, int lda, int ldb, int nkb)
{
    const unsigned short* A = blockIdx.z ? A1 : A0;
    const unsigned short* B = blockIdx.z ? B1 : B0;
    float* Cf = (float*)(blockIdx.z ? C1v : C0v);
    unsigned short* Cb = (unsigned short*)(blockIdx.z ? C1v : C0v);

    __shared__ __align__(16) unsigned short As[128][72];
    __shared__ __align__(16) unsigned short Bs[128][72];

    const int tid = threadIdx.x;
    const int lane = tid & 63, wv = tid >> 6;
    const int c = lane & 15, quad = lane >> 4;
    const int wm = wv >> 1, wn = wv & 1;
    const int rowBase = blockIdx.y << 7;
    const int colBase = blockIdx.x << 7;

    floatx4 acc[4][4];
#pragma unroll
    for (int i = 0; i < 4; ++i)
#pragma unroll
        for (int j = 0; j < 4; ++j) acc[i][j] = (floatx4){0.f,0.f,0.f,0.f};

    bf16x8 ar[4], br[4];
    {
#pragma unroll
        for (int i = 0; i < 4; ++i) {
            int f = tid + (i << 8);
            int r = f >> 3, kbk = (f & 7) << 3;
            ar[i] = *(const bf16x8*)(A + (size_t)(rowBase + r) * lda + kbk);
            br[i] = *(const bf16x8*)(B + (size_t)(colBase + r) * ldb + kbk);
        }
    }
    for (int kb = 0; kb < nkb; ++kb) {
        __syncthreads();
#pragma unroll
        for (int i = 0; i < 4; ++i) {
            int f = tid + (i << 8);
            int r = f >> 3, kbk = (f & 7) << 3;
            *(bf16x8*)&As[r][kbk] = ar[i];
            *(bf16x8*)&Bs[r][kbk] = br[i];
        }
        __syncthreads();
        if (kb + 1 < nkb) {
            int kn = kb + 1, aoff, boff;
            if (SPLIT3) {
                int t = kn >> 4, kk = (kn & 15) << 6;
                aoff = ((t == 1) ? 1024 : 0) + kk;
                boff = ((t == 2) ? 1024 : 0) + kk;
            } else { aoff = boff = kn << 6; }
#pragma unroll
            for (int i = 0; i < 4; ++i) {
                int f = tid + (i << 8);
                int r = f >> 3, kbk = (f & 7) << 3;
                ar[i] = *(const bf16x8*)(A + (size_t)(rowBase + r) * lda + aoff + kbk);
                br[i] = *(const bf16x8*)(B + (size_t)(colBase + r) * ldb + boff + kbk);
            }
        }
#pragma unroll
        for (int ks = 0; ks < 2; ++ks) {
            bf16x8 af[4], bfr[4];
#pragma unroll
            for (int i = 0; i < 4; ++i) {
                af[i]  = *(const bf16x8*)&As[wm*64 + i*16 + c][ks*32 + quad*8];
                bfr[i] = *(const bf16x8*)&Bs[wn*64 + i*16 + c][ks*32 + quad*8];
            }
#pragma unroll
            for (int mi = 0; mi < 4; ++mi)
#pragma unroll
                for (int ni = 0; ni < 4; ++ni)
                    acc[mi][ni] = MFMA16(af[mi], bfr[ni], acc[mi][ni]);
        }
    }
    const int row0 = rowBase + wm*64 + quad*4;
    if (EPI == 0) {
        const int col0 = colBase + wn*64 + c;
#pragma unroll
        for (int mi = 0; mi < 4; ++mi)
#pragma unroll
            for (int r = 0; r < 4; ++r) {
                size_t ro = (size_t)(row0 + mi*16 + r) * 1024 + col0;
#pragma unroll
                for (int ni = 0; ni < 4; ++ni)
                    Cf[ro + ni*16] = acc[mi][ni][r];
            }
    } else if (EPI == 1) {
        const int h = (colBase >> 6) + wn;       // head index
#pragma unroll
        for (int mi = 0; mi < 4; ++mi)
#pragma unroll
            for (int r = 0; r < 4; ++r) {
                int row = row0 + mi*16 + r;
                int b = row >> 11, s = row & 2047;
                size_t base = ((size_t)((b<<4) | h) * 2048 + s) * 128;
#pragma unroll
                for (int ni = 0; ni < 4; ++ni) {
                    int d = ni*16 + c;
                    float x = acc[mi][ni][r];
                    unsigned short hb = f2bf(x);
                    Cb[base + d]      = hb;
                    Cb[base + 64 + d] = f2bf(x - bf2f(hb));
                }
            }
    } else {  // EPI == 2: Vt[bh][d][s]
        const int h = (colBase >> 6) + wn;
#pragma unroll
        for (int mi = 0; mi < 4; ++mi) {
            int row = row0 + mi*16;
            int b = row >> 11, s = row & 2047;
#pragma unroll
            for (int ni = 0; ni < 4; ++ni) {
                int d = ni*16 + c;
                size_t base = ((size_t)((b<<4)|h) * 64 + d) * 2048 + s;
                ushort4 o4;
                o4.x = f2bf(acc[mi][ni][0]); o4.y = f2bf(acc[mi][ni][1]);
                o4.z = f2bf(acc[mi][ni][2]); o4.w = f2bf(acc[mi][ni][3]);
                *(ushort4*)(Cb + base) = o4;
            }
        }
    }
}

// ---------------------------------------------------------------------------
// def_w from pre-split inputs: qd/kd are [bh][s][hi|lo] bf16.
// ---------------------------------------------------------------------------
__global__ __launch_bounds__(256)
void defw_mfma(const unsigned short* __restrict__ qd,
               const unsigned short* __restrict__ kd,
               float* __restrict__ defw)
{
    __shared__ __align__(16) unsigned short Ks[64][136];
    const int tid = threadIdx.x;
    const int wv = tid >> 6, lane = tid & 63;
    const int c = lane & 15, quad = lane >> 4;
    const int bh = blockIdx.y;
    const int qbase = blockIdx.x << 6;
    const int trow = tid >> 2, seg = tid & 3;

    bf16x8 qhi[2], qlo[2];
    {
        const unsigned short* qrow =
            qd + ((size_t)bh*2048 + qbase + 16*wv + c)*128 + quad*8;
        qhi[0] = *(const bf16x8*)(qrow);
        qhi[1] = *(const bf16x8*)(qrow + 32);
        qlo[0] = *(const bf16x8*)(qrow + 64);
        qlo[1] = *(const bf16x8*)(qrow + 96);
    }
    float rs[4] = {0.f,0.f,0.f,0.f};
    const unsigned short* kbase = kd + (size_t)bh*2048*128;
    for (int kt = 0; kt < SEQ; kt += 64) {
        __syncthreads();
        {   // pure-copy staging: 4 x b128 per thread
            const unsigned short* kp = kbase + (size_t)(kt + trow)*128 + seg*32;
            *(bf16x8*)&Ks[trow][seg*32 + 0]  = *(const bf16x8*)(kp);
            *(bf16x8*)&Ks[trow][seg*32 + 8]  = *(const bf16x8*)(kp + 8);
            *(bf16x8*)&Ks[trow][seg*32 + 16] = *(const bf16x8*)(kp + 16);
            *(bf16x8*)&Ks[trow][seg*32 + 24] = *(const bf16x8*)(kp + 24);
        }
        __syncthreads();
#pragma unroll
        for (int nk = 0; nk < 4; ++nk) {
            const unsigned short* kr = &Ks[16*nk + c][quad*8];
            bf16x8 bh0 = *(const bf16x8*)(kr);
            bf16x8 bh1 = *(const bf16x8*)(kr + 32);
            bf16x8 bl0 = *(const bf16x8*)(kr + 64);
            bf16x8 bl1 = *(const bf16x8*)(kr + 96);
            floatx4 s = {0.f,0.f,0.f,0.f};
            s = MFMA16(qhi[0], bh0, s);
            s = MFMA16(qhi[1], bh1, s);
            s = MFMA16(qlo[0], bh0, s);
            s = MFMA16(qlo[1], bh1, s);
            s = MFMA16(qhi[0], bl0, s);
            s = MFMA16(qhi[1], bl1, s);
#pragma unroll
            for (int r = 0; r < 4; ++r)
                rs[r] += 1.f / (1.f + __expf(-0.125f * s[r]));
        }
    }
#pragma unroll
    for (int r = 0; r < 4; ++r) {
        float vv = rs[r];
        vv += __shfl_xor(vv, 1, 16);
        vv += __shfl_xor(vv, 2, 16);
        vv += __shfl_xor(vv, 4, 16);
        vv += __shfl_xor(vv, 8, 16);
        rs[r] = vv;
    }
    if (c == 0) {
#pragma unroll
        for (int r = 0; r < 4; ++r)
            defw[(size_t)bh*SEQ + qbase + 16*wv + 4*quad + r] = rs[r];
    }
}

// ---------------------------------------------------------------------------
// Flash attention from pre-split q/k ([bh][s][hi|lo]) and V^T ([bh][d][s]).
// All staging is pure b128 copy; no per-tile conversions.
// ---------------------------------------------------------------------------
__global__ __launch_bounds__(256)
void flash_mfma(const unsigned short* __restrict__ q,
                const unsigned short* __restrict__ kk,
                const unsigned short* __restrict__ vt,
                const float* __restrict__ dwg,
                unsigned short* __restrict__ o)
{
    __shared__ __align__(16) unsigned short Ks[64][136];
    __shared__ __align__(16) unsigned short Vs[64][72];
    __shared__ __align__(16) unsigned short Ps[4][16][72];
    const int tid = threadIdx.x;
    const int wv = tid >> 6, lane = tid & 63;
    const int c = lane & 15, quad = lane >> 4;
    const int bh = blockIdx.y, b = bh >> 4, h = bh & 15;
    const int qbase = blockIdx.x << 6;
    const int trow = tid >> 2, seg = tid & 3;

    bf16x8 qhi[2], qlo[2];
    {
        const unsigned short* qrow =
            q + ((size_t)bh*2048 + qbase + 16*wv + c)*128 + quad*8;
        qhi[0] = *(const bf16x8*)(qrow);
        qhi[1] = *(const bf16x8*)(qrow + 32);
        qlo[0] = *(const bf16x8*)(qrow + 64);
        qlo[1] = *(const bf16x8*)(qrow + 96);
    }
    floatx4 Oa[4];
#pragma unroll
    for (int nd = 0; nd < 4; ++nd) Oa[nd] = (floatx4){0.f,0.f,0.f,0.f};
    float mrun[4], lrun[4];
#pragma unroll
    for (int r = 0; r < 4; ++r) { mrun[r] = -3.0e38f; lrun[r] = 0.f; }

    const unsigned short* kbase = kk + (size_t)bh*2048*128;
    const unsigned short* vbase = vt + (size_t)bh*64*2048;

    for (int kt = 0; kt < SEQ; kt += 64) {
        __syncthreads();   // prev tile frag reads done
        {   // K staging: pure copy, 4 x b128
            const unsigned short* kp = kbase + (size_t)(kt + trow)*128 + seg*32;
            *(bf16x8*)&Ks[trow][seg*32 + 0]  = *(const bf16x8*)(kp);
            *(bf16x8*)&Ks[trow][seg*32 + 8]  = *(const bf16x8*)(kp + 8);
            *(bf16x8*)&Ks[trow][seg*32 + 16] = *(const bf16x8*)(kp + 16);
            *(bf16x8*)&Ks[trow][seg*32 + 24] = *(const bf16x8*)(kp + 24);
        }
        {   // V staging: pure row copy, 2 x b128 (row = dim d, cols = t)
            const unsigned short* vp = vbase + (size_t)trow*2048 + kt + seg*16;
            *(bf16x8*)&Vs[trow][seg*16 + 0] = *(const bf16x8*)(vp);
            *(bf16x8*)&Vs[trow][seg*16 + 8] = *(const bf16x8*)(vp + 8);
        }
        float dwv[4];
#pragma unroll
        for (int n = 0; n < 4; ++n)
            dwv[n] = dwg[(size_t)bh*SEQ + kt + 16*n + c];
        __syncthreads();   // K,V tiles visible

        floatx4 z[4];
#pragma unroll
        for (int nk = 0; nk < 4; ++nk) {
            const unsigned short* kr = &Ks[16*nk + c][quad*8];
            bf16x8 bh0 = *(const bf16x8*)(kr);
            bf16x8 bh1 = *(const bf16x8*)(kr + 32);
            bf16x8 bl0 = *(const bf16x8*)(kr + 64);
            bf16x8 bl1 = *(const bf16x8*)(kr + 96);
            floatx4 s = {0.f,0.f,0.f,0.f};
            s = MFMA16(qhi[0], bh0, s);
            s = MFMA16(qhi[1], bh1, s);
            s = MFMA16(qlo[0], bh0, s);
            s = MFMA16(qlo[1], bh1, s);
            s = MFMA16(qhi[0], bl0, s);
            s = MFMA16(qhi[1], bl1, s);
            float w = 0.125f * dwv[nk];
#pragma unroll
            for (int r = 0; r < 4; ++r) z[nk][r] = s[r] * w;
        }
        // online softmax in registers
        float alpha[4];
#pragma unroll
        for (int r = 0; r < 4; ++r) {
            float tm = fmaxf(fmaxf(z[0][r], z[1][r]), fmaxf(z[2][r], z[3][r]));
            tm = fmaxf(tm, __shfl_xor(tm, 1, 16));
            tm = fmaxf(tm, __shfl_xor(tm, 2, 16));
            tm = fmaxf(tm, __shfl_xor(tm, 4, 16));
            tm = fmaxf(tm, __shfl_xor(tm, 8, 16));
            float mn = fmaxf(mrun[r], tm);
            alpha[r] = __expf(mrun[r] - mn);
            mrun[r] = mn;
        }
#pragma unroll
        for (int r = 0; r < 4; ++r) {
            float rsum = 0.f;
#pragma unroll
            for (int n = 0; n < 4; ++n) {
                z[n][r] = __expf(z[n][r] - mrun[r]);
                rsum += z[n][r];
            }
            rsum += __shfl_xor(rsum, 1, 16);
            rsum += __shfl_xor(rsum, 2, 16);
            rsum += __shfl_xor(rsum, 4, 16);
            rsum += __shfl_xor(rsum, 8, 16);
            lrun[r] = lrun[r] * alpha[r] + rsum;
        }
        // P -> per-wave LDS slice (C-layout -> A-layout), no barrier needed
#pragma unroll
        for (int n = 0; n < 4; ++n)
#pragma unroll
            for (int r = 0; r < 4; ++r)
                Ps[wv][4*quad + r][16*n + c] = f2bf(z[n][r]);
#pragma unroll
        for (int nd = 0; nd < 4; ++nd)
#pragma unroll
            for (int r = 0; r < 4; ++r)
                Oa[nd][r] *= alpha[r];
        bf16x8 pa0 = *(const bf16x8*)&Ps[wv][c][quad*8];
        bf16x8 pa1 = *(const bf16x8*)&Ps[wv][c][32 + quad*8];
#pragma unroll
        for (int nd = 0; nd < 4; ++nd) {
            const int d = 16*nd + c;
            bf16x8 v0 = *(const bf16x8*)&Vs[d][quad*8];
            bf16x8 v1 = *(const bf16x8*)&Vs[d][32 + quad*8];
            Oa[nd] = MFMA16(pa0, v0, Oa[nd]);
            Oa[nd] = MFMA16(pa1, v1, Oa[nd]);
        }
    }
    float invl[4];
#pragma unroll
    for (int r = 0; r < 4; ++r) invl[r] = 1.f / lrun[r];
    unsigned short* orow = o + ((size_t)(b*SEQ + qbase + 16*wv + 4*quad))*DIM + h*HDIM;
#pragma unroll
    for (int nd = 0; nd < 4; ++nd)
#pragma unroll
        for (int r = 0; r < 4; ++r)
            orow[(size_t)r*DIM + 16*nd + c] = f2bf(Oa[nd][r] * invl[r]);
}

// ---------------------------------------------------------------------------
extern "C" void kernel_launch(void* const* d_in, const int* in_sizes, int n_in,
                              void* d_out, int out_size, void* d_ws, size_t ws_size,
                              hipStream_t stream)
{
    (void)in_sizes; (void)n_in; (void)out_size; (void)ws_size;
    const float* qi     = (const float*)d_in[0];
    const float* ki     = (const float*)d_in[1];
    const float* vi     = (const float*)d_in[2];
    const float* Wq     = (const float*)d_in[3];
    const float* Wq_def = (const float*)d_in[4];
    const float* Wk     = (const float*)d_in[5];
    const float* Wk_def = (const float*)d_in[6];
    const float* Wv     = (const float*)d_in[7];
    const float* Wo     = (const float*)d_in[8];
    float* out = (float*)d_out;

    char* ws = (char*)d_ws;
    const size_t MB = 1024 * 1024;
    // phase 1 (projections):
    unsigned short* Aq  = (unsigned short*)(ws +  0*MB);  // [4096][2048] hi|lo, 16 MB
    unsigned short* Ak  = (unsigned short*)(ws + 16*MB);  // 16 MB
    unsigned short* Bx  = (unsigned short*)(ws + 32*MB);  // 4 MB  (Bqd then Bq)
    unsigned short* By  = (unsigned short*)(ws + 36*MB);  // 4 MB  (Bkd then Bk)
    unsigned short* qs  = (unsigned short*)(ws + 40*MB);  // [32bh][2048][128] = 16 MB (qds then qs)
    unsigned short* ks  = (unsigned short*)(ws + 56*MB);  // 16 MB (kds then ks)
    float*          dw  = (float*)(ws + 72*MB);           // 256 KB
    // phase 2 overlays (Aq/Ak dead):
    unsigned short* Av  = (unsigned short*)(ws +  0*MB);  // 8 MB
    unsigned short* Bv  = (unsigned short*)(ws +  8*MB);  // 2 MB
    unsigned short* Bo  = (unsigned short*)(ws + 10*MB);  // 2 MB
    unsigned short* Vt  = (unsigned short*)(ws + 12*MB);  // [32bh][64][2048] = 8 MB
    unsigned short* att = (unsigned short*)(ws + 20*MB);  // [4096][1024] bf16 = 8 MB

    dim3 cb(256);
    dim3 gP(DIM/128, MR/128, 2);   // (8, 32, 2)
    dim3 gS(DIM/128, MR/128, 1);
    dim3 gA(SEQ/64, BSZ*NH);       // (32, 32)

    // 1. split-convert qi, ki, def weights
    conv_split<<<dim3(4096, 4), cb, 0, stream>>>(
        qi, ki, Wq_def, Wk_def, Aq, Ak, Bx, By, MR, MR, DIM, DIM);
    // 2. q_def, k_def -> split-bh layout
    gemm_mfma<1, true><<<gP, cb, 0, stream>>>(Aq, Ak, Bx, By, qs, ks, 2048, 2048, 48);
    // 3. defeasible weights
    defw_mfma<<<gA, cb, 0, stream>>>(qs, ks, dw);
    // 4. main weights (overwrite def weights)
    conv_split<<<dim3(1024, 2), cb, 0, stream>>>(
        Wq, Wk, Wq, Wk, Bx, By, Bx, By, DIM, DIM, 0, 0);
    // 5. q, k -> split-bh layout (overwrite qds, kds)
    gemm_mfma<1, true><<<gP, cb, 0, stream>>>(Aq, Ak, Bx, By, qs, ks, 2048, 2048, 48);
    // 6. hi converts for v path (Aq/Ak dead)
    conv_hi<<<dim3(4096, 3), cb, 0, stream>>>(vi, Wv, Wo, Av, Bv, Bo,
                                              MR*DIM, DIM*DIM, DIM*DIM);
    // 7. v projection -> V^T layout
    gemm_mfma<2, false><<<gS, cb, 0, stream>>>(Av, Av, Bv, Bv, Vt, Vt, 1024, 1024, 16);
    // 8. attention
    flash_mfma<<<gA, cb, 0, stream>>>(qs, ks, Vt, dw, att);
    // 9. output projection
    gemm_mfma<0, false><<<gS, cb, 0, stream>>>(att, att, Bo, Bo, out, out, 1024, 1024, 16);
}

// Round 5
// 530.742 us; speedup vs baseline: 3.3980x; 1.0046x over previous
//
#include <hip/hip_runtime.h>
#include <math.h>

#define BSZ 2
#define SEQ 2048
#define DIM 1024
#define NH 16
#define HDIM 64
#define MR (BSZ*SEQ)   // 4096 rows

typedef __attribute__((ext_vector_type(8))) short bf16x8;
typedef __attribute__((ext_vector_type(4))) float floatx4;

static __device__ __forceinline__ unsigned short f2bf(float x) {
    unsigned u = __float_as_uint(x);
    u += 0x7fffu + ((u >> 16) & 1u);
    return (unsigned short)(u >> 16);
}
static __device__ __forceinline__ float bf2f(unsigned short h) {
    return __uint_as_float(((unsigned)h) << 16);
}
#define MFMA16(a,b,c) __builtin_amdgcn_mfma_f32_16x16x32_bf16((a),(b),(c),0,0,0)

// ---------------------------------------------------------------------------
// conv_split: fp32 [rows][1024] -> bf16 [rows][2048] as [hi | lo]
// ---------------------------------------------------------------------------
__global__ __launch_bounds__(256)
void conv_split(const float* p0, const float* p1, const float* p2,
                const float* p3,
                unsigned short* o0, unsigned short* o1, unsigned short* o2,
                unsigned short* o3,
                int r0, int r1, int r2, int r3)
{
    const float* pin; unsigned short* pout; int rows;
    switch (blockIdx.y) {
        case 0: pin=p0; pout=o0; rows=r0; break;
        case 1: pin=p1; pout=o1; rows=r1; break;
        case 2: pin=p2; pout=o2; rows=r2; break;
        default: pin=p3; pout=o3; rows=r3; break;
    }
    size_t idx = (size_t)blockIdx.x * 256 + threadIdx.x;   // group of 4 floats
    if (idx * 4 >= (size_t)rows * DIM) return;
    size_t row = (idx * 4) >> 10;
    int col = (int)((idx * 4) & 1023);
    float4 f = *(const float4*)(pin + idx * 4);
    ushort4 h, l;
    h.x = f2bf(f.x); l.x = f2bf(f.x - bf2f(h.x));
    h.y = f2bf(f.y); l.y = f2bf(f.y - bf2f(h.y));
    h.z = f2bf(f.z); l.z = f2bf(f.z - bf2f(h.z));
    h.w = f2bf(f.w); l.w = f2bf(f.w - bf2f(h.w));
    *(ushort4*)(pout + row * 2048 + col)        = h;
    *(ushort4*)(pout + row * 2048 + 1024 + col) = l;
}

// conv_hi: fp32 flat -> bf16 flat (hi only), 3 matrices via blockIdx.y
__global__ __launch_bounds__(256)
void conv_hi(const float* p0, const float* p1, const float* p2,
             unsigned short* o0, unsigned short* o1, unsigned short* o2,
             int n0, int n1, int n2)
{
    const float* pin; unsigned short* pout; int n;
    switch (blockIdx.y) {
        case 0: pin=p0; pout=o0; n=n0; break;
        case 1: pin=p1; pout=o1; n=n1; break;
        default: pin=p2; pout=o2; n=n2; break;
    }
    size_t idx = (size_t)blockIdx.x * 256 + threadIdx.x;
    if (idx * 4 >= (size_t)n) return;
    float4 f = *(const float4*)(pin + idx * 4);
    ushort4 h;
    h.x = f2bf(f.x); h.y = f2bf(f.y); h.z = f2bf(f.z); h.w = f2bf(f.w);
    *(ushort4*)(pout + idx * 4) = h;
}

// ---------------------------------------------------------------------------
// bf16 MFMA GEMM (unchanged from round 4 — verified)
// ---------------------------------------------------------------------------
template<int EPI, bool SPLIT3>
__global__ __launch_bounds__(256)
void gemm_mfma(const unsigned short* __restrict__ A0, const unsigned short* __restrict__ A1,
               const unsigned short* __restrict__ B0, const unsigned short* __restrict__ B1,
               void* C0v, void* C1v, int lda, int ldb, int nkb)
{
    const unsigned short* A = blockIdx.z ? A1 : A0;
    const unsigned short* B = blockIdx.z ? B1 : B0;
    float* Cf = (float*)(blockIdx.z ? C1v : C0v);
    unsigned short* Cb = (unsigned short*)(blockIdx.z ? C1v : C0v);

    __shared__ __align__(16) unsigned short As[128][72];
    __shared__ __align__(16) unsigned short Bs[128][72];

    const int tid = threadIdx.x;
    const int lane = tid & 63, wv = tid >> 6;
    const int c = lane & 15, quad = lane >> 4;
    const int wm = wv >> 1, wn = wv & 1;
    const int rowBase = blockIdx.y << 7;
    const int colBase = blockIdx.x << 7;

    floatx4 acc[4][4];
#pragma unroll
    for (int i = 0; i < 4; ++i)
#pragma unroll
        for (int j = 0; j < 4; ++j) acc[i][j] = (floatx4){0.f,0.f,0.f,0.f};

    bf16x8 ar[4], br[4];
    {
#pragma unroll
        for (int i = 0; i < 4; ++i) {
            int f = tid + (i << 8);
            int r = f >> 3, kbk = (f & 7) << 3;
            ar[i] = *(const bf16x8*)(A + (size_t)(rowBase + r) * lda + kbk);
            br[i] = *(const bf16x8*)(B + (size_t)(colBase + r) * ldb + kbk);
        }
    }
    for (int kb = 0; kb < nkb; ++kb) {
        __syncthreads();
#pragma unroll
        for (int i = 0; i < 4; ++i) {
            int f = tid + (i << 8);
            int r = f >> 3, kbk = (f & 7) << 3;
            *(bf16x8*)&As[r][kbk] = ar[i];
            *(bf16x8*)&Bs[r][kbk] = br[i];
        }
        __syncthreads();
        if (kb + 1 < nkb) {
            int kn = kb + 1, aoff, boff;
            if (SPLIT3) {
                int t = kn >> 4, kk = (kn & 15) << 6;
                aoff = ((t == 1) ? 1024 : 0) + kk;
                boff = ((t == 2) ? 1024 : 0) + kk;
            } else { aoff = boff = kn << 6; }
#pragma unroll
            for (int i = 0; i < 4; ++i) {
                int f = tid + (i << 8);
                int r = f >> 3, kbk = (f & 7) << 3;
                ar[i] = *(const bf16x8*)(A + (size_t)(rowBase + r) * lda + aoff + kbk);
                br[i] = *(const bf16x8*)(B + (size_t)(colBase + r) * ldb + boff + kbk);
            }
        }
#pragma unroll
        for (int ks = 0; ks < 2; ++ks) {
            bf16x8 af[4], bfr[4];
#pragma unroll
            for (int i = 0; i < 4; ++i) {
                af[i]  = *(const bf16x8*)&As[wm*64 + i*16 + c][ks*32 + quad*8];
                bfr[i] = *(const bf16x8*)&Bs[wn*64 + i*16 + c][ks*32 + quad*8];
            }
#pragma unroll
            for (int mi = 0; mi < 4; ++mi)
#pragma unroll
                for (int ni = 0; ni < 4; ++ni)
                    acc[mi][ni] = MFMA16(af[mi], bfr[ni], acc[mi][ni]);
        }
    }
    const int row0 = rowBase + wm*64 + quad*4;
    if (EPI == 0) {
        const int col0 = colBase + wn*64 + c;
#pragma unroll
        for (int mi = 0; mi < 4; ++mi)
#pragma unroll
            for (int r = 0; r < 4; ++r) {
                size_t ro = (size_t)(row0 + mi*16 + r) * 1024 + col0;
#pragma unroll
                for (int ni = 0; ni < 4; ++ni)
                    Cf[ro + ni*16] = acc[mi][ni][r];
            }
    } else if (EPI == 1) {
        const int h = (colBase >> 6) + wn;       // head index
#pragma unroll
        for (int mi = 0; mi < 4; ++mi)
#pragma unroll
            for (int r = 0; r < 4; ++r) {
                int row = row0 + mi*16 + r;
                int b = row >> 11, s = row & 2047;
                size_t base = ((size_t)((b<<4) | h) * 2048 + s) * 128;
#pragma unroll
                for (int ni = 0; ni < 4; ++ni) {
                    int d = ni*16 + c;
                    float x = acc[mi][ni][r];
                    unsigned short hb = f2bf(x);
                    Cb[base + d]      = hb;
                    Cb[base + 64 + d] = f2bf(x - bf2f(hb));
                }
            }
    } else {  // EPI == 2: Vt[bh][d][s]
        const int h = (colBase >> 6) + wn;
#pragma unroll
        for (int mi = 0; mi < 4; ++mi) {
            int row = row0 + mi*16;
            int b = row >> 11, s = row & 2047;
#pragma unroll
            for (int ni = 0; ni < 4; ++ni) {
                int d = ni*16 + c;
                size_t base = ((size_t)((b<<4)|h) * 64 + d) * 2048 + s;
                ushort4 o4;
                o4.x = f2bf(acc[mi][ni][0]); o4.y = f2bf(acc[mi][ni][1]);
                o4.z = f2bf(acc[mi][ni][2]); o4.w = f2bf(acc[mi][ni][3]);
                *(ushort4*)(Cb + base) = o4;
            }
        }
    }
}

// ---------------------------------------------------------------------------
// def_w: Q-tile 128, 4 waves x M=32 (2 m-frags). Writes def_w * 0.125.
// ---------------------------------------------------------------------------
__global__ __launch_bounds__(256)
void defw_mfma(const unsigned short* __restrict__ qd,
               const unsigned short* __restrict__ kd,
               float* __restrict__ defw)
{
    __shared__ __align__(16) unsigned short Ks[64][136];
    const int tid = threadIdx.x;
    const int wv = tid >> 6, lane = tid & 63;
    const int c = lane & 15, quad = lane >> 4;
    const int bh = blockIdx.y;
    const int qbase = blockIdx.x << 7;
    const int trow = tid >> 2, seg = tid & 3;

    bf16x8 qhi[2][2], qlo[2][2];
#pragma unroll
    for (int mi = 0; mi < 2; ++mi) {
        const unsigned short* qrow =
            qd + ((size_t)bh*2048 + qbase + wv*32 + mi*16 + c)*128 + quad*8;
        qhi[mi][0] = *(const bf16x8*)(qrow);
        qhi[mi][1] = *(const bf16x8*)(qrow + 32);
        qlo[mi][0] = *(const bf16x8*)(qrow + 64);
        qlo[mi][1] = *(const bf16x8*)(qrow + 96);
    }
    float rs[2][4] = {{0.f,0.f,0.f,0.f},{0.f,0.f,0.f,0.f}};
    const unsigned short* kbase = kd + (size_t)bh*2048*128;
    for (int kt = 0; kt < SEQ; kt += 64) {
        __syncthreads();
        {   // pure-copy staging: 4 x b128 per thread
            const unsigned short* kp = kbase + (size_t)(kt + trow)*128 + seg*32;
            *(bf16x8*)&Ks[trow][seg*32 + 0]  = *(const bf16x8*)(kp);
            *(bf16x8*)&Ks[trow][seg*32 + 8]  = *(const bf16x8*)(kp + 8);
            *(bf16x8*)&Ks[trow][seg*32 + 16] = *(const bf16x8*)(kp + 16);
            *(bf16x8*)&Ks[trow][seg*32 + 24] = *(const bf16x8*)(kp + 24);
        }
        __syncthreads();
#pragma unroll
        for (int nk = 0; nk < 4; ++nk) {
            const unsigned short* kr = &Ks[16*nk + c][quad*8];
            bf16x8 bh0 = *(const bf16x8*)(kr);
            bf16x8 bh1 = *(const bf16x8*)(kr + 32);
            bf16x8 bl0 = *(const bf16x8*)(kr + 64);
            bf16x8 bl1 = *(const bf16x8*)(kr + 96);
#pragma unroll
            for (int mi = 0; mi < 2; ++mi) {
                floatx4 s = {0.f,0.f,0.f,0.f};
                s = MFMA16(qhi[mi][0], bh0, s);
                s = MFMA16(qhi[mi][1], bh1, s);
                s = MFMA16(qlo[mi][0], bh0, s);
                s = MFMA16(qlo[mi][1], bh1, s);
                s = MFMA16(qhi[mi][0], bl0, s);
                s = MFMA16(qhi[mi][1], bl1, s);
#pragma unroll
                for (int r = 0; r < 4; ++r)
                    rs[mi][r] += 1.f / (1.f + __expf(-0.125f * s[r]));
            }
        }
    }
#pragma unroll
    for (int mi = 0; mi < 2; ++mi)
#pragma unroll
        for (int r = 0; r < 4; ++r) {
            float vv = rs[mi][r];
            vv += __shfl_xor(vv, 1, 16);
            vv += __shfl_xor(vv, 2, 16);
            vv += __shfl_xor(vv, 4, 16);
            vv += __shfl_xor(vv, 8, 16);
            if (c == 0)
                defw[(size_t)bh*SEQ + qbase + wv*32 + mi*16 + 4*quad + r]
                    = vv * 0.125f;   // pre-fold the 1/sqrt(HD) scale
        }
}

// ---------------------------------------------------------------------------
// Flash attention: Q-tile 128, 4 waves x M=32. Split-bf16 QK^T, bf16 PV.
// P stage stride 76 (conflict-free scalar writes). dwg pre-scaled by 0.125.
// ---------------------------------------------------------------------------
__global__ __launch_bounds__(256)
void flash_mfma(const unsigned short* __restrict__ q,
                const unsigned short* __restrict__ kk,
                const unsigned short* __restrict__ vt,
                const float* __restrict__ dwg,
                unsigned short* __restrict__ o)
{
    __shared__ __align__(16) unsigned short Ks[64][136];
    __shared__ __align__(16) unsigned short Vs[64][72];
    __shared__ __align__(16) unsigned short Ps[4][32][76];
    const int tid = threadIdx.x;
    const int wv = tid >> 6, lane = tid & 63;
    const int c = lane & 15, quad = lane >> 4;
    const int bh = blockIdx.y, b = bh >> 4, h = bh & 15;
    const int qbase = blockIdx.x << 7;
    const int trow = tid >> 2, seg = tid & 3;

    bf16x8 qhi[2][2], qlo[2][2];
#pragma unroll
    for (int mi = 0; mi < 2; ++mi) {
        const unsigned short* qrow =
            q + ((size_t)bh*2048 + qbase + wv*32 + mi*16 + c)*128 + quad*8;
        qhi[mi][0] = *(const bf16x8*)(qrow);
        qhi[mi][1] = *(const bf16x8*)(qrow + 32);
        qlo[mi][0] = *(const bf16x8*)(qrow + 64);
        qlo[mi][1] = *(const bf16x8*)(qrow + 96);
    }
    floatx4 Oa[2][4];
#pragma unroll
    for (int mi = 0; mi < 2; ++mi)
#pragma unroll
        for (int nd = 0; nd < 4; ++nd) Oa[mi][nd] = (floatx4){0.f,0.f,0.f,0.f};
    float mrun[2][4], lrun[2][4];
#pragma unroll
    for (int mi = 0; mi < 2; ++mi)
#pragma unroll
        for (int r = 0; r < 4; ++r) { mrun[mi][r] = -3.0e38f; lrun[mi][r] = 0.f; }

    const unsigned short* kbase = kk + (size_t)bh*2048*128;
    const unsigned short* vbase = vt + (size_t)bh*64*2048;

    for (int kt = 0; kt < SEQ; kt += 64) {
        __syncthreads();   // prev tile frag reads done
        {   // K staging: pure copy, 4 x b128
            const unsigned short* kp = kbase + (size_t)(kt + trow)*128 + seg*32;
            *(bf16x8*)&Ks[trow][seg*32 + 0]  = *(const bf16x8*)(kp);
            *(bf16x8*)&Ks[trow][seg*32 + 8]  = *(const bf16x8*)(kp + 8);
            *(bf16x8*)&Ks[trow][seg*32 + 16] = *(const bf16x8*)(kp + 16);
            *(bf16x8*)&Ks[trow][seg*32 + 24] = *(const bf16x8*)(kp + 24);
        }
        {   // V staging: pure row copy, 2 x b128 (row = dim d, cols = t)
            const unsigned short* vp = vbase + (size_t)trow*2048 + kt + seg*16;
            *(bf16x8*)&Vs[trow][seg*16 + 0] = *(const bf16x8*)(vp);
            *(bf16x8*)&Vs[trow][seg*16 + 8] = *(const bf16x8*)(vp + 8);
        }
        float dwv[4];
#pragma unroll
        for (int n = 0; n < 4; ++n)
            dwv[n] = dwg[(size_t)bh*SEQ + kt + 16*n + c];
        __syncthreads();   // K,V tiles visible

        // QK^T (split bf16, 3-term), both m-frags share the K frag reads
        floatx4 z[2][4];
#pragma unroll
        for (int nk = 0; nk < 4; ++nk) {
            const unsigned short* kr = &Ks[16*nk + c][quad*8];
            bf16x8 bh0 = *(const bf16x8*)(kr);
            bf16x8 bh1 = *(const bf16x8*)(kr + 32);
            bf16x8 bl0 = *(const bf16x8*)(kr + 64);
            bf16x8 bl1 = *(const bf16x8*)(kr + 96);
#pragma unroll
            for (int mi = 0; mi < 2; ++mi) {
                floatx4 s = {0.f,0.f,0.f,0.f};
                s = MFMA16(qhi[mi][0], bh0, s);
                s = MFMA16(qhi[mi][1], bh1, s);
                s = MFMA16(qlo[mi][0], bh0, s);
                s = MFMA16(qlo[mi][1], bh1, s);
                s = MFMA16(qhi[mi][0], bl0, s);
                s = MFMA16(qhi[mi][1], bl1, s);
#pragma unroll
                for (int r = 0; r < 4; ++r) z[mi][nk][r] = s[r] * dwv[nk];
            }
        }
        // online softmax in registers
        float alpha[2][4];
#pragma unroll
        for (int mi = 0; mi < 2; ++mi)
#pragma unroll
            for (int r = 0; r < 4; ++r) {
                float tm = fmaxf(fmaxf(z[mi][0][r], z[mi][1][r]),
                                 fmaxf(z[mi][2][r], z[mi][3][r]));
                tm = fmaxf(tm, __shfl_xor(tm, 1, 16));
                tm = fmaxf(tm, __shfl_xor(tm, 2, 16));
                tm = fmaxf(tm, __shfl_xor(tm, 4, 16));
                tm = fmaxf(tm, __shfl_xor(tm, 8, 16));
                float mn = fmaxf(mrun[mi][r], tm);
                alpha[mi][r] = __expf(mrun[mi][r] - mn);
                mrun[mi][r] = mn;
            }
#pragma unroll
        for (int mi = 0; mi < 2; ++mi)
#pragma unroll
            for (int r = 0; r < 4; ++r) {
                float rsum = 0.f;
#pragma unroll
                for (int n = 0; n < 4; ++n) {
                    z[mi][n][r] = __expf(z[mi][n][r] - mrun[mi][r]);
                    rsum += z[mi][n][r];
                }
                rsum += __shfl_xor(rsum, 1, 16);
                rsum += __shfl_xor(rsum, 2, 16);
                rsum += __shfl_xor(rsum, 4, 16);
                rsum += __shfl_xor(rsum, 8, 16);
                lrun[mi][r] = lrun[mi][r] * alpha[mi][r] + rsum;
            }
        // P -> per-wave LDS slice (C-layout -> A-layout), stride 76
#pragma unroll
        for (int mi = 0; mi < 2; ++mi)
#pragma unroll
            for (int n = 0; n < 4; ++n)
#pragma unroll
                for (int r = 0; r < 4; ++r)
                    Ps[wv][mi*16 + 4*quad + r][16*n + c] = f2bf(z[mi][n][r]);
        // rescale O
#pragma unroll
        for (int mi = 0; mi < 2; ++mi)
#pragma unroll
            for (int nd = 0; nd < 4; ++nd)
#pragma unroll
                for (int r = 0; r < 4; ++r)
                    Oa[mi][nd][r] *= alpha[mi][r];
        // P A-frags (same wave wrote them; lgkmcnt ordering suffices)
        bf16x8 pa[2][2];
#pragma unroll
        for (int mi = 0; mi < 2; ++mi) {
            pa[mi][0] = *(const bf16x8*)&Ps[wv][mi*16 + c][quad*8];
            pa[mi][1] = *(const bf16x8*)&Ps[wv][mi*16 + c][32 + quad*8];
        }
        // PV: V frags shared across m-frags
#pragma unroll
        for (int nd = 0; nd < 4; ++nd) {
            const int d = 16*nd + c;
            bf16x8 v0 = *(const bf16x8*)&Vs[d][quad*8];
            bf16x8 v1 = *(const bf16x8*)&Vs[d][32 + quad*8];
#pragma unroll
            for (int mi = 0; mi < 2; ++mi) {
                Oa[mi][nd] = MFMA16(pa[mi][0], v0, Oa[mi][nd]);
                Oa[mi][nd] = MFMA16(pa[mi][1], v1, Oa[mi][nd]);
            }
        }
    }
#pragma unroll
    for (int mi = 0; mi < 2; ++mi) {
        float invl[4];
#pragma unroll
        for (int r = 0; r < 4; ++r) invl[r] = 1.f / lrun[mi][r];
        unsigned short* orow =
            o + ((size_t)(b*SEQ + qbase + wv*32 + mi*16 + 4*quad))*DIM + h*HDIM;
#pragma unroll
        for (int nd = 0; nd < 4; ++nd)
#pragma unroll
            for (int r = 0; r < 4; ++r)
                orow[(size_t)r*DIM + 16*nd + c] = f2bf(Oa[mi][nd][r] * invl[r]);
    }
}

// ---------------------------------------------------------------------------
extern "C" void kernel_launch(void* const* d_in, const int* in_sizes, int n_in,
                              void* d_out, int out_size, void* d_ws, size_t ws_size,
                              hipStream_t stream)
{
    (void)in_sizes; (void)n_in; (void)out_size; (void)ws_size;
    const float* qi     = (const float*)d_in[0];
    const float* ki     = (const float*)d_in[1];
    const float* vi     = (const float*)d_in[2];
    const float* Wq     = (const float*)d_in[3];
    const float* Wq_def = (const float*)d_in[4];
    const float* Wk     = (const float*)d_in[5];
    const float* Wk_def = (const float*)d_in[6];
    const float* Wv     = (const float*)d_in[7];
    const float* Wo     = (const float*)d_in[8];
    float* out = (float*)d_out;

    char* ws = (char*)d_ws;
    const size_t MB = 1024 * 1024;
    // phase 1 (projections):
    unsigned short* Aq  = (unsigned short*)(ws +  0*MB);  // [4096][2048] hi|lo, 16 MB
    unsigned short* Ak  = (unsigned short*)(ws + 16*MB);  // 16 MB
    unsigned short* Bx  = (unsigned short*)(ws + 32*MB);  // 4 MB  (Bqd then Bq)
    unsigned short* By  = (unsigned short*)(ws + 36*MB);  // 4 MB  (Bkd then Bk)
    unsigned short* qs  = (unsigned short*)(ws + 40*MB);  // [32bh][2048][128] = 16 MB
    unsigned short* ks  = (unsigned short*)(ws + 56*MB);  // 16 MB
    float*          dw  = (float*)(ws + 72*MB);           // 256 KB
    // phase 2 overlays (Aq/Ak dead):
    unsigned short* Av  = (unsigned short*)(ws +  0*MB);  // 8 MB
    unsigned short* Bv  = (unsigned short*)(ws +  8*MB);  // 2 MB
    unsigned short* Bo  = (unsigned short*)(ws + 10*MB);  // 2 MB
    unsigned short* Vt  = (unsigned short*)(ws + 12*MB);  // [32bh][64][2048] = 8 MB
    unsigned short* att = (unsigned short*)(ws + 20*MB);  // [4096][1024] bf16 = 8 MB

    dim3 cb(256);
    dim3 gP(DIM/128, MR/128, 2);    // (8, 32, 2)
    dim3 gS(DIM/128, MR/128, 1);
    dim3 gA(SEQ/128, BSZ*NH);       // (16, 32) — Q-tile 128

    // 1. split-convert qi, ki, def weights
    conv_split<<<dim3(4096, 4), cb, 0, stream>>>(
        qi, ki, Wq_def, Wk_def, Aq, Ak, Bx, By, MR, MR, DIM, DIM);
    // 2. q_def, k_def -> split-bh layout
    gemm_mfma<1, true><<<gP, cb, 0, stream>>>(Aq, Ak, Bx, By, qs, ks, 2048, 2048, 48);
    // 3. defeasible weights (pre-scaled by 0.125)
    defw_mfma<<<gA, cb, 0, stream>>>(qs, ks, dw);
    // 4. main weights (overwrite def weights)
    conv_split<<<dim3(1024, 2), cb, 0, stream>>>(
        Wq, Wk, Wq, Wk, Bx, By, Bx, By, DIM, DIM, 0, 0);
    // 5. q, k -> split-bh layout
    gemm_mfma<1, true><<<gP, cb, 0, stream>>>(Aq, Ak, Bx, By, qs, ks, 2048, 2048, 48);
    // 6. hi converts for v path (Aq/Ak dead)
    conv_hi<<<dim3(4096, 3), cb, 0, stream>>>(vi, Wv, Wo, Av, Bv, Bo,
                                              MR*DIM, DIM*DIM, DIM*DIM);
    // 7. v projection -> V^T layout
    gemm_mfma<2, false><<<gS, cb, 0, stream>>>(Av, Av, Bv, Bv, Vt, Vt, 1024, 1024, 16);
    // 8. attention
    flash_mfma<<<gA, cb, 0, stream>>>(qs, ks, Vt, dw, att);
    // 9. output projection
    gemm_mfma<0, false><<<gS, cb, 0, stream>>>(att, att, Bo, Bo, out, out, 1024, 1024, 16);
}

// Round 6
// 482.929 us; speedup vs baseline: 3.7344x; 1.0990x over previous
//
#include <hip/hip_runtime.h>
#include <math.h>

#define BSZ 2
#define SEQ 2048
#define DIM 1024
#define NH 16
#define HDIM 64
#define MR (BSZ*SEQ)   // 4096 rows

typedef __attribute__((ext_vector_type(8))) short bf16x8;
typedef __attribute__((ext_vector_type(4))) short bf16x4;
typedef __attribute__((ext_vector_type(4))) float floatx4;

static __device__ __forceinline__ unsigned short f2bf(float x) {
    unsigned u = __float_as_uint(x);
    u += 0x7fffu + ((u >> 16) & 1u);
    return (unsigned short)(u >> 16);
}
static __device__ __forceinline__ float bf2f(unsigned short h) {
    return __uint_as_float(((unsigned)h) << 16);
}
#define MFMA16(a,b,c) __builtin_amdgcn_mfma_f32_16x16x32_bf16((a),(b),(c),0,0,0)

// 16x16x16 bf16 MFMA (K=16): A,B = 4 bf16/lane at k=quad*4+j.
static __device__ __forceinline__ floatx4 pv_mfma(bf16x4 a, bf16x4 b, floatx4 c) {
#if __has_builtin(__builtin_amdgcn_mfma_f32_16x16x16bf16_1k)
    return __builtin_amdgcn_mfma_f32_16x16x16bf16_1k(a, b, c, 0, 0, 0);
#else
    // zero-padded K=32 fallback: slots j=4..7 contribute 0 on both operands
    bf16x8 a8 = {a[0],a[1],a[2],a[3],0,0,0,0};
    bf16x8 b8 = {b[0],b[1],b[2],b[3],0,0,0,0};
    return MFMA16(a8, b8, c);
#endif
}

// ---------------------------------------------------------------------------
// conv_split: fp32 [rows][1024] -> bf16 [rows][2048] as [hi | lo]
// ---------------------------------------------------------------------------
__global__ __launch_bounds__(256)
void conv_split(const float* p0, const float* p1, const float* p2,
                const float* p3,
                unsigned short* o0, unsigned short* o1, unsigned short* o2,
                unsigned short* o3,
                int r0, int r1, int r2, int r3)
{
    const float* pin; unsigned short* pout; int rows;
    switch (blockIdx.y) {
        case 0: pin=p0; pout=o0; rows=r0; break;
        case 1: pin=p1; pout=o1; rows=r1; break;
        case 2: pin=p2; pout=o2; rows=r2; break;
        default: pin=p3; pout=o3; rows=r3; break;
    }
    size_t idx = (size_t)blockIdx.x * 256 + threadIdx.x;   // group of 4 floats
    if (idx * 4 >= (size_t)rows * DIM) return;
    size_t row = (idx * 4) >> 10;
    int col = (int)((idx * 4) & 1023);
    float4 f = *(const float4*)(pin + idx * 4);
    ushort4 h, l;
    h.x = f2bf(f.x); l.x = f2bf(f.x - bf2f(h.x));
    h.y = f2bf(f.y); l.y = f2bf(f.y - bf2f(h.y));
    h.z = f2bf(f.z); l.z = f2bf(f.z - bf2f(h.z));
    h.w = f2bf(f.w); l.w = f2bf(f.w - bf2f(h.w));
    *(ushort4*)(pout + row * 2048 + col)        = h;
    *(ushort4*)(pout + row * 2048 + 1024 + col) = l;
}

// conv_hi: fp32 flat -> bf16 flat (hi only), 3 matrices via blockIdx.y
__global__ __launch_bounds__(256)
void conv_hi(const float* p0, const float* p1, const float* p2,
             unsigned short* o0, unsigned short* o1, unsigned short* o2,
             int n0, int n1, int n2)
{
    const float* pin; unsigned short* pout; int n;
    switch (blockIdx.y) {
        case 0: pin=p0; pout=o0; n=n0; break;
        case 1: pin=p1; pout=o1; n=n1; break;
        default: pin=p2; pout=o2; n=n2; break;
    }
    size_t idx = (size_t)blockIdx.x * 256 + threadIdx.x;
    if (idx * 4 >= (size_t)n) return;
    float4 f = *(const float4*)(pin + idx * 4);
    ushort4 h;
    h.x = f2bf(f.x); h.y = f2bf(f.y); h.z = f2bf(f.z); h.w = f2bf(f.w);
    *(ushort4*)(pout + idx * 4) = h;
}

// ---------------------------------------------------------------------------
// bf16 MFMA GEMM (unchanged — verified)
// ---------------------------------------------------------------------------
template<int EPI, bool SPLIT3>
__global__ __launch_bounds__(256)
void gemm_mfma(const unsigned short* __restrict__ A0, const unsigned short* __restrict__ A1,
               const unsigned short* __restrict__ B0, const unsigned short* __restrict__ B1,
               void* C0v, void* C1v, int lda, int ldb, int nkb)
{
    const unsigned short* A = blockIdx.z ? A1 : A0;
    const unsigned short* B = blockIdx.z ? B1 : B0;
    float* Cf = (float*)(blockIdx.z ? C1v : C0v);
    unsigned short* Cb = (unsigned short*)(blockIdx.z ? C1v : C0v);

    __shared__ __align__(16) unsigned short As[128][72];
    __shared__ __align__(16) unsigned short Bs[128][72];

    const int tid = threadIdx.x;
    const int lane = tid & 63, wv = tid >> 6;
    const int c = lane & 15, quad = lane >> 4;
    const int wm = wv >> 1, wn = wv & 1;
    const int rowBase = blockIdx.y << 7;
    const int colBase = blockIdx.x << 7;

    floatx4 acc[4][4];
#pragma unroll
    for (int i = 0; i < 4; ++i)
#pragma unroll
        for (int j = 0; j < 4; ++j) acc[i][j] = (floatx4){0.f,0.f,0.f,0.f};

    bf16x8 ar[4], br[4];
    {
#pragma unroll
        for (int i = 0; i < 4; ++i) {
            int f = tid + (i << 8);
            int r = f >> 3, kbk = (f & 7) << 3;
            ar[i] = *(const bf16x8*)(A + (size_t)(rowBase + r) * lda + kbk);
            br[i] = *(const bf16x8*)(B + (size_t)(colBase + r) * ldb + kbk);
        }
    }
    for (int kb = 0; kb < nkb; ++kb) {
        __syncthreads();
#pragma unroll
        for (int i = 0; i < 4; ++i) {
            int f = tid + (i << 8);
            int r = f >> 3, kbk = (f & 7) << 3;
            *(bf16x8*)&As[r][kbk] = ar[i];
            *(bf16x8*)&Bs[r][kbk] = br[i];
        }
        __syncthreads();
        if (kb + 1 < nkb) {
            int kn = kb + 1, aoff, boff;
            if (SPLIT3) {
                int t = kn >> 4, kk = (kn & 15) << 6;
                aoff = ((t == 1) ? 1024 : 0) + kk;
                boff = ((t == 2) ? 1024 : 0) + kk;
            } else { aoff = boff = kn << 6; }
#pragma unroll
            for (int i = 0; i < 4; ++i) {
                int f = tid + (i << 8);
                int r = f >> 3, kbk = (f & 7) << 3;
                ar[i] = *(const bf16x8*)(A + (size_t)(rowBase + r) * lda + aoff + kbk);
                br[i] = *(const bf16x8*)(B + (size_t)(colBase + r) * ldb + boff + kbk);
            }
        }
#pragma unroll
        for (int ks = 0; ks < 2; ++ks) {
            bf16x8 af[4], bfr[4];
#pragma unroll
            for (int i = 0; i < 4; ++i) {
                af[i]  = *(const bf16x8*)&As[wm*64 + i*16 + c][ks*32 + quad*8];
                bfr[i] = *(const bf16x8*)&Bs[wn*64 + i*16 + c][ks*32 + quad*8];
            }
#pragma unroll
            for (int mi = 0; mi < 4; ++mi)
#pragma unroll
                for (int ni = 0; ni < 4; ++ni)
                    acc[mi][ni] = MFMA16(af[mi], bfr[ni], acc[mi][ni]);
        }
    }
    const int row0 = rowBase + wm*64 + quad*4;
    if (EPI == 0) {
        const int col0 = colBase + wn*64 + c;
#pragma unroll
        for (int mi = 0; mi < 4; ++mi)
#pragma unroll
            for (int r = 0; r < 4; ++r) {
                size_t ro = (size_t)(row0 + mi*16 + r) * 1024 + col0;
#pragma unroll
                for (int ni = 0; ni < 4; ++ni)
                    Cf[ro + ni*16] = acc[mi][ni][r];
            }
    } else if (EPI == 1) {
        const int h = (colBase >> 6) + wn;       // head index
#pragma unroll
        for (int mi = 0; mi < 4; ++mi)
#pragma unroll
            for (int r = 0; r < 4; ++r) {
                int row = row0 + mi*16 + r;
                int b = row >> 11, s = row & 2047;
                size_t base = ((size_t)((b<<4) | h) * 2048 + s) * 128;
#pragma unroll
                for (int ni = 0; ni < 4; ++ni) {
                    int d = ni*16 + c;
                    float x = acc[mi][ni][r];
                    unsigned short hb = f2bf(x);
                    Cb[base + d]      = hb;
                    Cb[base + 64 + d] = f2bf(x - bf2f(hb));
                }
            }
    } else {  // EPI == 2: Vt[bh][d][s]
        const int h = (colBase >> 6) + wn;
#pragma unroll
        for (int mi = 0; mi < 4; ++mi) {
            int row = row0 + mi*16;
            int b = row >> 11, s = row & 2047;
#pragma unroll
            for (int ni = 0; ni < 4; ++ni) {
                int d = ni*16 + c;
                size_t base = ((size_t)((b<<4)|h) * 64 + d) * 2048 + s;
                ushort4 o4;
                o4.x = f2bf(acc[mi][ni][0]); o4.y = f2bf(acc[mi][ni][1]);
                o4.z = f2bf(acc[mi][ni][2]); o4.w = f2bf(acc[mi][ni][3]);
                *(ushort4*)(Cb + base) = o4;
            }
        }
    }
}

// ---------------------------------------------------------------------------
// def_w: Q-tile 128, 4 waves x M=32, K-tile register prefetch.
// Writes def_w * 0.125.
// ---------------------------------------------------------------------------
__global__ __launch_bounds__(256)
void defw_mfma(const unsigned short* __restrict__ qd,
               const unsigned short* __restrict__ kd,
               float* __restrict__ defw)
{
    __shared__ __align__(16) unsigned short Ks[64][136];
    const int tid = threadIdx.x;
    const int wv = tid >> 6, lane = tid & 63;
    const int c = lane & 15, quad = lane >> 4;
    const int bh = blockIdx.y;
    const int qbase = blockIdx.x << 7;
    const int trow = tid >> 2, seg = tid & 3;

    bf16x8 qhi[2][2], qlo[2][2];
#pragma unroll
    for (int mi = 0; mi < 2; ++mi) {
        const unsigned short* qrow =
            qd + ((size_t)bh*2048 + qbase + wv*32 + mi*16 + c)*128 + quad*8;
        qhi[mi][0] = *(const bf16x8*)(qrow);
        qhi[mi][1] = *(const bf16x8*)(qrow + 32);
        qlo[mi][0] = *(const bf16x8*)(qrow + 64);
        qlo[mi][1] = *(const bf16x8*)(qrow + 96);
    }
    float rs[2][4] = {{0.f,0.f,0.f,0.f},{0.f,0.f,0.f,0.f}};
    const unsigned short* kbase = kd + (size_t)bh*2048*128;
    bf16x8 kpre[4];
    {
        const unsigned short* kp = kbase + (size_t)trow*128 + seg*32;
#pragma unroll
        for (int u = 0; u < 4; ++u) kpre[u] = *(const bf16x8*)(kp + 8*u);
    }
    for (int kt = 0; kt < SEQ; kt += 64) {
        __syncthreads();
#pragma unroll
        for (int u = 0; u < 4; ++u) *(bf16x8*)&Ks[trow][seg*32 + 8*u] = kpre[u];
        __syncthreads();
        if (kt + 64 < SEQ) {
            const unsigned short* kp = kbase + (size_t)(kt + 64 + trow)*128 + seg*32;
#pragma unroll
            for (int u = 0; u < 4; ++u) kpre[u] = *(const bf16x8*)(kp + 8*u);
        }
#pragma unroll
        for (int nk = 0; nk < 4; ++nk) {
            const unsigned short* kr = &Ks[16*nk + c][quad*8];
            bf16x8 kh0 = *(const bf16x8*)(kr);
            bf16x8 kh1 = *(const bf16x8*)(kr + 32);
            bf16x8 kl0 = *(const bf16x8*)(kr + 64);
            bf16x8 kl1 = *(const bf16x8*)(kr + 96);
#pragma unroll
            for (int mi = 0; mi < 2; ++mi) {
                floatx4 s = {0.f,0.f,0.f,0.f};
                s = MFMA16(qhi[mi][0], kh0, s);
                s = MFMA16(qhi[mi][1], kh1, s);
                s = MFMA16(qlo[mi][0], kh0, s);
                s = MFMA16(qlo[mi][1], kh1, s);
                s = MFMA16(qhi[mi][0], kl0, s);
                s = MFMA16(qhi[mi][1], kl1, s);
#pragma unroll
                for (int r = 0; r < 4; ++r)
                    rs[mi][r] += 1.f / (1.f + __expf(-0.125f * s[r]));
            }
        }
    }
#pragma unroll
    for (int mi = 0; mi < 2; ++mi)
#pragma unroll
        for (int r = 0; r < 4; ++r) {
            float vv = rs[mi][r];
            vv += __shfl_xor(vv, 1, 16);
            vv += __shfl_xor(vv, 2, 16);
            vv += __shfl_xor(vv, 4, 16);
            vv += __shfl_xor(vv, 8, 16);
            if (c == 0)
                defw[(size_t)bh*SEQ + qbase + wv*32 + mi*16 + 4*quad + r]
                    = vv * 0.125f;   // pre-fold the 1/sqrt(HD) scale
        }
}

// ---------------------------------------------------------------------------
// Flash attention, transposed-score formulation:
//   z^T[t][s] = (K·Q^T)·dw[t]  — C-layout col=s (lane), rows=t (quad*4+r)
//   softmax over t: in-register + 2 wave shuffles (no butterflies)
//   P^T in C-layout IS the B-frag of 16x16x16 MFMA -> PV with NO LDS round trip
//   O^T[d][s] accumulated; K/V tiles register-prefetched.
// ---------------------------------------------------------------------------
__global__ __launch_bounds__(256)
void flash_mfma(const unsigned short* __restrict__ q,
                const unsigned short* __restrict__ kk,
                const unsigned short* __restrict__ vt,
                const float* __restrict__ dwg,
                unsigned short* __restrict__ o)
{
    __shared__ __align__(16) unsigned short Ks[64][136];
    __shared__ __align__(16) unsigned short Vs[64][72];
    const int tid = threadIdx.x;
    const int wv = tid >> 6, lane = tid & 63;
    const int c = lane & 15, quad = lane >> 4;
    const int bh = blockIdx.y, b = bh >> 4, h = bh & 15;
    const int qbase = blockIdx.x << 7;
    const int trow = tid >> 2, seg = tid & 3;

    // Q fragments (B-operand of swapped QK^T; layout same as before)
    bf16x8 qhi[2][2], qlo[2][2];
#pragma unroll
    for (int mi = 0; mi < 2; ++mi) {
        const unsigned short* qrow =
            q + ((size_t)bh*2048 + qbase + wv*32 + mi*16 + c)*128 + quad*8;
        qhi[mi][0] = *(const bf16x8*)(qrow);
        qhi[mi][1] = *(const bf16x8*)(qrow + 32);
        qlo[mi][0] = *(const bf16x8*)(qrow + 64);
        qlo[mi][1] = *(const bf16x8*)(qrow + 96);
    }
    floatx4 Oa[4][2];    // [nd][mi], O^T[d][s]
#pragma unroll
    for (int nd = 0; nd < 4; ++nd)
#pragma unroll
        for (int mi = 0; mi < 2; ++mi) Oa[nd][mi] = (floatx4){0.f,0.f,0.f,0.f};
    float mrun[2] = {-3.0e38f, -3.0e38f}, lrun[2] = {0.f, 0.f};

    const unsigned short* kbase = kk + (size_t)bh*2048*128;
    const unsigned short* vbase = vt + (size_t)bh*64*2048;

    bf16x8 kpre[4], vpre[2];
    {
        const unsigned short* kp = kbase + (size_t)trow*128 + seg*32;
#pragma unroll
        for (int u = 0; u < 4; ++u) kpre[u] = *(const bf16x8*)(kp + 8*u);
        const unsigned short* vp = vbase + (size_t)trow*2048 + seg*16;
        vpre[0] = *(const bf16x8*)(vp);
        vpre[1] = *(const bf16x8*)(vp + 8);
    }

    for (int kt = 0; kt < SEQ; kt += 64) {
        __syncthreads();   // prev tile frag reads done
#pragma unroll
        for (int u = 0; u < 4; ++u) *(bf16x8*)&Ks[trow][seg*32 + 8*u] = kpre[u];
        *(bf16x8*)&Vs[trow][seg*16 + 0] = vpre[0];
        *(bf16x8*)&Vs[trow][seg*16 + 8] = vpre[1];
        // def weights for this tile's t rows: t = nk*16 + quad*4 + r
        float dwf[4][4];
#pragma unroll
        for (int nk = 0; nk < 4; ++nk) {
            float4 d4 = *(const float4*)&dwg[(size_t)bh*SEQ + kt + nk*16 + quad*4];
            dwf[nk][0]=d4.x; dwf[nk][1]=d4.y; dwf[nk][2]=d4.z; dwf[nk][3]=d4.w;
        }
        __syncthreads();   // K,V tiles visible
        if (kt + 64 < SEQ) {   // prefetch next tile during compute
            const unsigned short* kp = kbase + (size_t)(kt + 64 + trow)*128 + seg*32;
#pragma unroll
            for (int u = 0; u < 4; ++u) kpre[u] = *(const bf16x8*)(kp + 8*u);
            const unsigned short* vp = vbase + (size_t)trow*2048 + (kt + 64) + seg*16;
            vpre[0] = *(const bf16x8*)(vp);
            vpre[1] = *(const bf16x8*)(vp + 8);
        }

        // z^T = K·Q^T (split bf16, 3-term); A=K frags shared across mi
        float z[2][4][4];   // [mi][nk][r]: value at t=nk*16+quad*4+r, s=mi*16+c
#pragma unroll
        for (int nk = 0; nk < 4; ++nk) {
            const unsigned short* kr = &Ks[16*nk + c][quad*8];
            bf16x8 kh0 = *(const bf16x8*)(kr);
            bf16x8 kh1 = *(const bf16x8*)(kr + 32);
            bf16x8 kl0 = *(const bf16x8*)(kr + 64);
            bf16x8 kl1 = *(const bf16x8*)(kr + 96);
#pragma unroll
            for (int mi = 0; mi < 2; ++mi) {
                floatx4 s = {0.f,0.f,0.f,0.f};
                s = MFMA16(kh0, qhi[mi][0], s);
                s = MFMA16(kh1, qhi[mi][1], s);
                s = MFMA16(kh0, qlo[mi][0], s);
                s = MFMA16(kh1, qlo[mi][1], s);
                s = MFMA16(kl0, qhi[mi][0], s);
                s = MFMA16(kl1, qhi[mi][1], s);
#pragma unroll
                for (int r = 0; r < 4; ++r) z[mi][nk][r] = s[r] * dwf[nk][r];
            }
        }
        // online softmax over t: in-register + 2 wave shuffles per reduction
        float alpha[2];
#pragma unroll
        for (int mi = 0; mi < 2; ++mi) {
            float tm = z[mi][0][0];
#pragma unroll
            for (int nk = 0; nk < 4; ++nk)
#pragma unroll
                for (int r = 0; r < 4; ++r) tm = fmaxf(tm, z[mi][nk][r]);
            tm = fmaxf(tm, __shfl_xor(tm, 16));
            tm = fmaxf(tm, __shfl_xor(tm, 32));
            float mn = fmaxf(mrun[mi], tm);
            alpha[mi] = __expf(mrun[mi] - mn);
            mrun[mi] = mn;
            float rsum = 0.f;
#pragma unroll
            for (int nk = 0; nk < 4; ++nk)
#pragma unroll
                for (int r = 0; r < 4; ++r) {
                    z[mi][nk][r] = __expf(z[mi][nk][r] - mn);
                    rsum += z[mi][nk][r];
                }
            rsum += __shfl_xor(rsum, 16);
            rsum += __shfl_xor(rsum, 32);
            lrun[mi] = lrun[mi] * alpha[mi] + rsum;
        }
        // P B-frags directly from registers (C-layout == 16x16x16 B-layout)
        bf16x4 pb[2][4];
#pragma unroll
        for (int mi = 0; mi < 2; ++mi)
#pragma unroll
            for (int nk = 0; nk < 4; ++nk) {
                bf16x4 p;
                p[0] = (short)f2bf(z[mi][nk][0]);
                p[1] = (short)f2bf(z[mi][nk][1]);
                p[2] = (short)f2bf(z[mi][nk][2]);
                p[3] = (short)f2bf(z[mi][nk][3]);
                pb[mi][nk] = p;
            }
        // rescale O^T (alpha is per-lane uniform: all regs share s)
#pragma unroll
        for (int nd = 0; nd < 4; ++nd)
#pragma unroll
            for (int mi = 0; mi < 2; ++mi)
#pragma unroll
                for (int r = 0; r < 4; ++r)
                    Oa[nd][mi][r] *= alpha[mi];
        // PV: O^T[d][s] += V^T-frag(A) x P-frag(B), K=16 per step
#pragma unroll
        for (int ks = 0; ks < 4; ++ks)
#pragma unroll
            for (int nd = 0; nd < 4; ++nd) {
                bf16x4 va = *(const bf16x4*)&Vs[nd*16 + c][ks*16 + quad*4];
#pragma unroll
                for (int mi = 0; mi < 2; ++mi)
                    Oa[nd][mi] = pv_mfma(va, pb[mi][ks], Oa[nd][mi]);
            }
    }
    // epilogue: O^T[d][s] -> att[s][h*64+d], d=nd*16+quad*4+r contiguous
#pragma unroll
    for (int mi = 0; mi < 2; ++mi) {
        float invl = 1.f / lrun[mi];
        int s_abs = qbase + wv*32 + mi*16 + c;
        unsigned short* orow = o + ((size_t)(b*SEQ + s_abs))*DIM + h*HDIM;
#pragma unroll
        for (int nd = 0; nd < 4; ++nd) {
            ushort4 o4;
            o4.x = f2bf(Oa[nd][mi][0] * invl);
            o4.y = f2bf(Oa[nd][mi][1] * invl);
            o4.z = f2bf(Oa[nd][mi][2] * invl);
            o4.w = f2bf(Oa[nd][mi][3] * invl);
            *(ushort4*)(orow + nd*16 + quad*4) = o4;
        }
    }
}

// ---------------------------------------------------------------------------
extern "C" void kernel_launch(void* const* d_in, const int* in_sizes, int n_in,
                              void* d_out, int out_size, void* d_ws, size_t ws_size,
                              hipStream_t stream)
{
    (void)in_sizes; (void)n_in; (void)out_size; (void)ws_size;
    const float* qi     = (const float*)d_in[0];
    const float* ki     = (const float*)d_in[1];
    const float* vi     = (const float*)d_in[2];
    const float* Wq     = (const float*)d_in[3];
    const float* Wq_def = (const float*)d_in[4];
    const float* Wk     = (const float*)d_in[5];
    const float* Wk_def = (const float*)d_in[6];
    const float* Wv     = (const float*)d_in[7];
    const float* Wo     = (const float*)d_in[8];
    float* out = (float*)d_out;

    char* ws = (char*)d_ws;
    const size_t MB = 1024 * 1024;
    // phase 1 (projections):
    unsigned short* Aq  = (unsigned short*)(ws +  0*MB);  // [4096][2048] hi|lo, 16 MB
    unsigned short* Ak  = (unsigned short*)(ws + 16*MB);  // 16 MB
    unsigned short* Bx  = (unsigned short*)(ws + 32*MB);  // 4 MB  (Bqd then Bq)
    unsigned short* By  = (unsigned short*)(ws + 36*MB);  // 4 MB  (Bkd then Bk)
    unsigned short* qs  = (unsigned short*)(ws + 40*MB);  // [32bh][2048][128] = 16 MB
    unsigned short* ks  = (unsigned short*)(ws + 56*MB);  // 16 MB
    float*          dw  = (float*)(ws + 72*MB);           // 256 KB
    // phase 2 overlays (Aq/Ak dead):
    unsigned short* Av  = (unsigned short*)(ws +  0*MB);  // 8 MB
    unsigned short* Bv  = (unsigned short*)(ws +  8*MB);  // 2 MB
    unsigned short* Bo  = (unsigned short*)(ws + 10*MB);  // 2 MB
    unsigned short* Vt  = (unsigned short*)(ws + 12*MB);  // [32bh][64][2048] = 8 MB
    unsigned short* att = (unsigned short*)(ws + 20*MB);  // [4096][1024] bf16 = 8 MB

    dim3 cb(256);
    dim3 gP(DIM/128, MR/128, 2);    // (8, 32, 2)
    dim3 gS(DIM/128, MR/128, 1);
    dim3 gA(SEQ/128, BSZ*NH);       // (16, 32) — Q-tile 128

    // 1. split-convert qi, ki, def weights
    conv_split<<<dim3(4096, 4), cb, 0, stream>>>(
        qi, ki, Wq_def, Wk_def, Aq, Ak, Bx, By, MR, MR, DIM, DIM);
    // 2. q_def, k_def -> split-bh layout
    gemm_mfma<1, true><<<gP, cb, 0, stream>>>(Aq, Ak, Bx, By, qs, ks, 2048, 2048, 48);
    // 3. defeasible weights (pre-scaled by 0.125)
    defw_mfma<<<gA, cb, 0, stream>>>(qs, ks, dw);
    // 4. main weights (overwrite def weights)
    conv_split<<<dim3(1024, 2), cb, 0, stream>>>(
        Wq, Wk, Wq, Wk, Bx, By, Bx, By, DIM, DIM, 0, 0);
    // 5. q, k -> split-bh layout
    gemm_mfma<1, true><<<gP, cb, 0, stream>>>(Aq, Ak, Bx, By, qs, ks, 2048, 2048, 48);
    // 6. hi converts for v path (Aq/Ak dead)
    conv_hi<<<dim3(4096, 3), cb, 0, stream>>>(vi, Wv, Wo, Av, Bv, Bo,
                                              MR*DIM, DIM*DIM, DIM*DIM);
    // 7. v projection -> V^T layout
    gemm_mfma<2, false><<<gS, cb, 0, stream>>>(Av, Av, Bv, Bv, Vt, Vt, 1024, 1024, 16);
    // 8. attention
    flash_mfma<<<gA, cb, 0, stream>>>(qs, ks, Vt, dw, att);
    // 9. output projection
    gemm_mfma<0, false><<<gS, cb, 0, stream>>>(att, att, Bo, Bo, out, out, 1024, 1024, 16);
}